// Round 4
// baseline (709.812 us; speedup 1.0000x reference)
//
#include <hip/hip_runtime.h>
#include <hip/hip_bf16.h>

typedef __attribute__((ext_vector_type(8))) short sh8;
typedef __attribute__((ext_vector_type(4))) float f4;
typedef unsigned short ushort_t;
typedef unsigned int uint_t;

// ---------- fast transcendentals (fp32) ----------
__device__ __forceinline__ float fast_rcp(float x) {
    return __builtin_amdgcn_rcpf(x);
}
__device__ __forceinline__ float sigmoidf_(float x) {
    return fast_rcp(1.f + __expf(-x));
}
__device__ __forceinline__ float tanhf_fast(float x) {
    float ax = fabsf(x);
    float e  = __expf(-2.f * ax);
    float t  = (1.f - e) * fast_rcp(1.f + e);
    return copysignf(t, x);
}

// ---------- bf16 split helpers (truncation; hi+lo ~ 2^-17 rel) ----------
__device__ __forceinline__ ushort_t bf16hi(float x) {
    return (ushort_t)(__float_as_uint(x) >> 16);
}
__device__ __forceinline__ float bf16tof(ushort_t u) {
    return __uint_as_float(((uint_t)u) << 16);
}

// ---------- conv1 (1->10, 5x5 VALID) + maxpool2 + tanh ----------
// x: [B,784] as 28x28, out COMPACT: [B,144,10]
__global__ __launch_bounds__(256) void conv1_pool_tanh(
    const float* __restrict__ x, const float* __restrict__ w,
    const float* __restrict__ bias, float* __restrict__ out)
{
    __shared__ float sw[250];
    __shared__ float sb[10];
    int t = threadIdx.x;
    if (t < 250) sw[t] = w[t];
    if (t < 10)  sb[t] = bias[t];
    __syncthreads();

    int gp  = blockIdx.x * 256 + t;
    int b   = gp / 144;
    int pix = gp % 144;
    int py = pix / 12, px = pix % 12;

    const float* img = x + (long)b * 784 + (2 * py) * 28 + 2 * px;
    float r[6][6];
#pragma unroll
    for (int ry = 0; ry < 6; ++ry)
#pragma unroll
        for (int rx = 0; rx < 6; ++rx)
            r[ry][rx] = img[ry * 28 + rx];

    float* ob = out + ((long)b * 144 + pix) * 10;
    for (int oc = 0; oc < 10; ++oc) {
        float a0 = 0.f, a1 = 0.f, a2 = 0.f, a3 = 0.f;
#pragma unroll
        for (int ky = 0; ky < 5; ++ky)
#pragma unroll
            for (int kx = 0; kx < 5; ++kx) {
                float wv = sw[oc * 25 + ky * 5 + kx];
                a0 += wv * r[ky][kx];
                a1 += wv * r[ky][kx + 1];
                a2 += wv * r[ky + 1][kx];
                a3 += wv * r[ky + 1][kx + 1];
            }
        float m = fmaxf(fmaxf(a0, a1), fmaxf(a2, a3)) + sb[oc];
        ob[oc] = tanhf_fast(m);
    }
}

// ---------- MFMA 2D-LSTM ----------
// x compact [B, H*W, CIN]; Wx [5H,CIN], Whl/Whu [5H,HID], bias [5H]
// out compact [B, H*W, HID].
template<int H, int W, int HID, int CIN, int KV, int NK, int NW, int VSTR, int GSTR>
__global__ __launch_bounds__(NW * 64) void mdlstm_mfma(
    const float* __restrict__ x, const float* __restrict__ Wx,
    const float* __restrict__ Whl, const float* __restrict__ Whu,
    const float* __restrict__ bias, float* __restrict__ out)
{
    constexpr int N    = H * W;
    constexpr int NT   = NW * 64;
    constexpr int NEPI = 16 * HID;
    constexpr int HL0  = CIN, HU0 = CIN + HID;
    constexpr int NXA  = 16 * CIN;
    constexpr int NSTG = 16 * W * CIN;
    static_assert(NW * 16 >= 5 * HID, "tiles cover gate rows");
    static_assert(KV >= CIN + 2 * HID, "K covers V");
    static_assert(NEPI <= NT && NXA <= NT, "thread budget");

    __shared__ ushort_t sV[16][VSTR];
    __shared__ float    sG[16][GSTR];
    __shared__ uint_t   sHrow[W][16][HID];
    __shared__ uint_t   sXrow[2][W][16][CIN];

    const int tid  = threadIdx.x;
    const int lane = tid & 63;
    const int wid  = tid >> 6;
    const int lr   = lane & 15;
    const int lg   = lane >> 4;
    const long bB  = (long)blockIdx.x * 16;

    sh8 Ah[NK], Al[NK];
    {
        const int r = wid * 16 + lr;
#pragma unroll
        for (int ks = 0; ks < NK; ++ks) {
#pragma unroll
            for (int e = 0; e < 8; ++e) {
                int k = ks * 32 + lg * 8 + e;
                float wv = 0.f;
                if (r < 5 * HID) {
                    if (k < CIN)            wv = Wx[r * CIN + k];
                    else if (k < HL0 + HID) wv = Whl[r * HID + (k - HL0)];
                    else if (k < HU0 + HID) wv = Whu[r * HID + (k - HU0)];
                }
                ushort_t hi = bf16hi(wv);
                Ah[ks][e] = (short)hi;
                Al[ks][e] = (short)bf16hi(wv - bf16tof(hi));
            }
        }
    }
    f4 biasF;
#pragma unroll
    for (int q = 0; q < 4; ++q) {
        int rr = wid * 16 + lg * 4 + q;
        biasF[q] = (rr < 5 * HID) ? bias[rr] : 0.f;
    }

    for (int idx = tid; idx < 16 * VSTR; idx += NT) (&sV[0][0])[idx] = 0;
    for (int idx = tid; idx < W * 16 * HID; idx += NT) (&sHrow[0][0][0])[idx] = 0;

    for (int idx = tid; idx < NSTG; idx += NT) {
        int batch = idx / (W * CIN);
        int rr    = idx % (W * CIN);
        float xv  = x[(bB + batch) * (N * CIN) + rr];
        ushort_t hi = bf16hi(xv);
        ushort_t lo = bf16hi(xv - bf16tof(hi));
        sXrow[0][rr / CIN][batch][rr % CIN] = ((uint_t)hi << 16) | lo;
    }
    __syncthreads();
    if (tid < NXA) {
        int batch = tid & 15, c = tid >> 4;
        uint_t xv = sXrow[0][0][batch][c];
        sV[batch][c]      = (ushort_t)(xv >> 16);
        sV[batch][KV + c] = (ushort_t)(xv & 0xffff);
    }
    __syncthreads();

    const int batch_e = tid & 15, j_e = tid >> 4;
    float c_row[W];
#pragma unroll
    for (int q = 0; q < W; ++q) c_row[q] = 0.f;

    for (int i = 0; i < H; ++i) {
        float c_left = 0.f;
#pragma unroll
        for (int jc = 0; jc < W; ++jc) {
            {
                sh8 Bh[NK];
#pragma unroll
                for (int ks = 0; ks < NK; ++ks)
                    Bh[ks] = *(const sh8*)&sV[lr][ks * 32 + lg * 8];
                f4 acc = __builtin_amdgcn_mfma_f32_16x16x32_bf16(
                             Ah[0], Bh[0], biasF, 0, 0, 0);
#pragma unroll
                for (int ks = 1; ks < NK; ++ks)
                    acc = __builtin_amdgcn_mfma_f32_16x16x32_bf16(
                              Ah[ks], Bh[ks], acc, 0, 0, 0);
#pragma unroll
                for (int ks = 0; ks < NK; ++ks) {
                    sh8 Bl = *(const sh8*)&sV[lr][KV + ks * 32 + lg * 8];
                    acc = __builtin_amdgcn_mfma_f32_16x16x32_bf16(
                              Ah[ks], Bl, acc, 0, 0, 0);
                }
#pragma unroll
                for (int ks = 0; ks < NK; ++ks)
                    acc = __builtin_amdgcn_mfma_f32_16x16x32_bf16(
                              Al[ks], Bh[ks], acc, 0, 0, 0);
                *(f4*)&sG[lr][wid * 16 + lg * 4] = acc;
            }
            if (jc == 0 && i + 1 < H) {
                const int nb = (i + 1) & 1;
                for (int idx = tid; idx < NSTG; idx += NT) {
                    int batch = idx / (W * CIN);
                    int rr    = idx % (W * CIN);
                    float xv  = x[(bB + batch) * (N * CIN) + (i + 1) * (W * CIN) + rr];
                    ushort_t hi = bf16hi(xv);
                    ushort_t lo = bf16hi(xv - bf16tof(hi));
                    sXrow[nb][rr / CIN][batch][rr % CIN] = ((uint_t)hi << 16) | lo;
                }
            }
            __syncthreads();
            if (tid < NEPI) {
                float g[5];
#pragma unroll
                for (int p = 0; p < 5; ++p) g[p] = sG[batch_e][j_e + HID * p];
                float ig  = sigmoidf_(g[0]), f1g = sigmoidf_(g[1]);
                float f2g = sigmoidf_(g[2]), og  = sigmoidf_(g[3]);
                float gg  = tanhf_fast(g[4]);
                float cc  = f1g * c_left + f2g * c_row[jc] + ig * gg;
                float hh  = og * tanhf_fast(cc);
                c_row[jc] = cc;
                c_left    = cc;
                ushort_t hhi = bf16hi(hh);
                ushort_t hlo = bf16hi(hh - bf16tof(hhi));
                if (jc < W - 1) {
                    sV[batch_e][HL0 + j_e]      = hhi;
                    sV[batch_e][KV + HL0 + j_e] = hlo;
                }
                sHrow[jc][batch_e][j_e] = ((uint_t)hhi << 16) | hlo;
                out[(bB + batch_e) * (long)(N * HID) + (i * W + jc) * HID + j_e] = hh;
            }
            if (i * W + jc < H * W - 1) {
                const int jc2 = (jc == W - 1) ? 0 : jc + 1;
                const int ib  = (jc == W - 1) ? ((i + 1) & 1) : (i & 1);
                if (tid >= NT - NEPI) {
                    int t2 = tid - (NT - NEPI);
                    int batch = t2 & 15, j2 = t2 >> 4;
                    uint_t hv = sHrow[jc2][batch][j2];
                    sV[batch][HU0 + j2]      = (ushort_t)(hv >> 16);
                    sV[batch][KV + HU0 + j2] = (ushort_t)(hv & 0xffff);
                }
                if (tid < NXA) {
                    int batch = tid & 15, c = tid >> 4;
                    uint_t xv = sXrow[ib][jc2][batch][c];
                    sV[batch][c]      = (ushort_t)(xv >> 16);
                    sV[batch][KV + c] = (ushort_t)(xv & 0xffff);
                }
                if (jc == W - 1 && tid < NEPI) {
                    sV[batch_e][HL0 + j_e]      = 0;
                    sV[batch_e][KV + HL0 + j_e] = 0;
                }
            }
            __syncthreads();
        }
    }
}

// ---------- conv2 via tap-decomposed MFMA ----------
// in COMPACT [B,144,20] fp32; wt [30,20,5,5]; out COMPACT [B,16,30].
// Block = 1 image, 5 waves; wave wid = tx. For each tx: GEMM over k=(ty,ic):
// O[oc][n] += W[oc][ty,ic,tx] * I[ty,ic -> pos(n)+ty*12+tx].  bf16 hi/lo split.
// 5 tx-partials reduced with ds_add_f32; epilogue = bias + maxpool2x2 + tanh.
__global__ __launch_bounds__(320) void conv2_mfma(
    const float* __restrict__ in, const float* __restrict__ wt,
    const float* __restrict__ bias, float* __restrict__ out)
{
    __shared__ ushort_t sHi[144][40];   // img bf16 hi, k-slots 0..19 real, 20..31 zero
    __shared__ ushort_t sLo[144][40];   // img bf16 lo
    __shared__ float    sAcc[2][4][16][17]; // [m-tile][pixtile][col n][row oc(+pad)]
    __shared__ float    sB[30];

    const int tid  = threadIdx.x;
    const int lane = tid & 63;
    const int wid  = tid >> 6;          // = tx
    const int c    = lane & 15;         // A: M-row ; B/C: col (pixel)
    const int kg   = lane >> 4;         // k-group
    const long b   = blockIdx.x;

    // ---- A-frags in registers: Ah/Al[ty][m-tile] ----
    sh8 Ah[5][2], Al[5][2];
#pragma unroll
    for (int ks = 0; ks < 5; ++ks) {
#pragma unroll
        for (int m = 0; m < 2; ++m) {
#pragma unroll
            for (int e = 0; e < 8; ++e) {
                int ic = kg * 8 + e;
                int oc = m * 16 + c;
                float wv = (ic < 20 && oc < 30)
                         ? wt[((oc * 20 + ic) * 5 + ks) * 5 + wid] : 0.f;
                ushort_t hi = bf16hi(wv);
                Ah[ks][m][e] = (short)hi;
                Al[ks][m][e] = (short)bf16hi(wv - bf16tof(hi));
            }
        }
    }

    // ---- stage image (bf16 split, zero-padded k) + zero sAcc ----
    for (int idx = tid; idx < 144 * 40; idx += 320) {
        int pos = idx / 40, s = idx % 40;
        float v = (s < 20) ? in[b * 2880 + pos * 20 + s] : 0.f;
        ushort_t hi = bf16hi(v);
        sHi[pos][s] = hi;
        sLo[pos][s] = bf16hi(v - bf16tof(hi));
    }
    for (int idx = tid; idx < 2 * 4 * 16 * 17; idx += 320)
        (&sAcc[0][0][0][0])[idx] = 0.f;
    if (tid < 30) sB[tid] = bias[tid];
    __syncthreads();

    // ---- main: 4 pixel tiles x 5 K-steps x (2 M-tiles x 3 split terms) ----
    const int y0 = c >> 3, x = c & 7;   // conv pixel within tile: n = p*16+c
#pragma unroll
    for (int p = 0; p < 4; ++p) {
        const int pos = (2 * p + y0) * 12 + x + wid;
        const ushort_t* bh = &sHi[pos][kg * 8];
        const ushort_t* bl = &sLo[pos][kg * 8];
        f4 a0 = {0.f, 0.f, 0.f, 0.f};
        f4 a1 = {0.f, 0.f, 0.f, 0.f};
#pragma unroll
        for (int ks = 0; ks < 5; ++ks) {
            sh8 Bh = *(const sh8*)(bh + ks * 12 * 40);
            sh8 Bl = *(const sh8*)(bl + ks * 12 * 40);
            a0 = __builtin_amdgcn_mfma_f32_16x16x32_bf16(Ah[ks][0], Bh, a0, 0, 0, 0);
            a0 = __builtin_amdgcn_mfma_f32_16x16x32_bf16(Ah[ks][0], Bl, a0, 0, 0, 0);
            a0 = __builtin_amdgcn_mfma_f32_16x16x32_bf16(Al[ks][0], Bh, a0, 0, 0, 0);
            a1 = __builtin_amdgcn_mfma_f32_16x16x32_bf16(Ah[ks][1], Bh, a1, 0, 0, 0);
            a1 = __builtin_amdgcn_mfma_f32_16x16x32_bf16(Ah[ks][1], Bl, a1, 0, 0, 0);
            a1 = __builtin_amdgcn_mfma_f32_16x16x32_bf16(Al[ks][1], Bh, a1, 0, 0, 0);
        }
#pragma unroll
        for (int q = 0; q < 4; ++q) {
            atomicAdd(&sAcc[0][p][c][kg * 4 + q], a0[q]);
            atomicAdd(&sAcc[1][p][c][kg * 4 + q], a1[q]);
        }
    }
    __syncthreads();

    // ---- epilogue: bias + 2x2 maxpool + tanh, compact store [B,16,30] ----
    for (int idx = tid; idx < 480; idx += 320) {
        int pix = idx / 30, oc = idx % 30;
        int m = oc >> 4, r = oc & 15;
        int py = pix >> 2, px = pix & 3;
        float v = -1e30f;
#pragma unroll
        for (int dy = 0; dy < 2; ++dy)
#pragma unroll
            for (int dx = 0; dx < 2; ++dx) {
                int n = (2 * py + dy) * 8 + 2 * px + dx;
                v = fmaxf(v, sAcc[m][n >> 4][n & 15][r]);
            }
        out[b * 480 + idx] = tanhf_fast(v + sB[oc]);
    }
}

// ---------- fc1 (640->100) + tanh ----------
// in COMPACT [B,16,40] (k' = pix*40+hid); w [100,640] with k = hid*16+pix.
__global__ __launch_bounds__(256) void fc1_tanh(
    const float* __restrict__ in, const float* __restrict__ w,
    const float* __restrict__ bias, float* __restrict__ out)
{
    int t = threadIdx.x;
    int bblk = blockIdx.x & 15;
    int o    = blockIdx.x >> 4;
    long b = (long)bblk * 256 + t;
    const float* wr = w + o * 640;
    const float* xr = in + b * 640;
    float acc = 0.f;
#pragma unroll 4
    for (int pix = 0; pix < 16; ++pix) {
        const float* xp = xr + pix * 40;
#pragma unroll
        for (int hid = 0; hid < 40; hid += 4) {
            float4 xv = *(const float4*)(xp + hid);
            acc += wr[(hid + 0) * 16 + pix] * xv.x
                 + wr[(hid + 1) * 16 + pix] * xv.y
                 + wr[(hid + 2) * 16 + pix] * xv.z
                 + wr[(hid + 3) * 16 + pix] * xv.w;
        }
    }
    out[b * 100 + o] = tanhf_fast(acc + bias[o]);
}

// ---------- fc2 (100->10) + softmax ----------
__global__ __launch_bounds__(64) void fc2_softmax(
    const float* __restrict__ in, const float* __restrict__ w,
    const float* __restrict__ bias, float* __restrict__ out)
{
    long b = (long)blockIdx.x * 64 + threadIdx.x;
    const float* xr = in + b * 100;
    float logit[10];
#pragma unroll
    for (int o = 0; o < 10; ++o) logit[o] = bias[o];
    for (int k = 0; k < 100; ++k) {
        float xv = xr[k];
#pragma unroll
        for (int o = 0; o < 10; ++o) logit[o] += xv * w[o * 100 + k];
    }
    float m = logit[0];
#pragma unroll
    for (int o = 1; o < 10; ++o) m = fmaxf(m, logit[o]);
    float s = 0.f;
#pragma unroll
    for (int o = 0; o < 10; ++o) { logit[o] = __expf(logit[o] - m); s += logit[o]; }
    float inv = fast_rcp(s);
#pragma unroll
    for (int o = 0; o < 10; ++o) out[b * 10 + o] = logit[o] * inv;
}

extern "C" void kernel_launch(void* const* d_in, const int* in_sizes, int n_in,
                              void* d_out, int out_size, void* d_ws, size_t ws_size,
                              hipStream_t stream)
{
    const float* x    = (const float*)d_in[0];
    const float* c1w  = (const float*)d_in[1];
    const float* c1b  = (const float*)d_in[2];
    const float* m1Wx = (const float*)d_in[3];
    const float* m1Wl = (const float*)d_in[4];
    const float* m1Wu = (const float*)d_in[5];
    const float* m1b  = (const float*)d_in[6];
    const float* c2w  = (const float*)d_in[7];
    const float* c2b  = (const float*)d_in[8];
    const float* m2Wx = (const float*)d_in[9];
    const float* m2Wl = (const float*)d_in[10];
    const float* m2Wu = (const float*)d_in[11];
    const float* m2b  = (const float*)d_in[12];
    const float* f1w  = (const float*)d_in[13];
    const float* f1b  = (const float*)d_in[14];
    const float* f2w  = (const float*)d_in[15];
    const float* f2b  = (const float*)d_in[16];
    float* outp = (float*)d_out;

    char* ws = (char*)d_ws;
    float* a1 = (float*)ws;                 // [B,144,10] 23.6 MB
    float* h1 = (float*)(ws + 23592960);    // [B,144,20] 47.2 MB
    float* a2 = a1;                         // [B,16,30] reuse
    float* h2 = h1;                         // [B,16,40] reuse
    float* f1 = a1;                         // [B,100]   reuse

    conv1_pool_tanh<<<2304, 256, 0, stream>>>(x, c1w, c1b, a1);
    // m1: V=[x10|hl20|hu20] pad KV=64, NK=2, 7 M-tiles (112 rows)
    mdlstm_mfma<12, 12, 20, 10, 64, 2, 7, 136, 116><<<256, 448, 0, stream>>>(
        a1, m1Wx, m1Wl, m1Wu, m1b, h1);
    conv2_mfma<<<4096, 320, 0, stream>>>(h1, c2w, c2b, a2);
    // m2: V=[x30|hl40|hu40] pad KV=128, NK=4, 13 M-tiles (208 rows)
    mdlstm_mfma<4, 4, 40, 30, 128, 4, 13, 264, 212><<<256, 832, 0, stream>>>(
        a2, m2Wx, m2Wl, m2Wu, m2b, h2);
    fc1_tanh<<<1600, 256, 0, stream>>>(h2, f1w, f1b, f1);
    fc2_softmax<<<64, 64, 0, stream>>>(f1, f2w, f2b, outp);
}

// Round 5
// 523.535 us; speedup vs baseline: 1.3558x; 1.3558x over previous
//
#include <hip/hip_runtime.h>
#include <hip/hip_bf16.h>

typedef __attribute__((ext_vector_type(8))) short sh8;
typedef __attribute__((ext_vector_type(4))) float f4;
typedef unsigned short ushort_t;
typedef unsigned int uint_t;

// ---------- fast transcendentals (fp32) ----------
__device__ __forceinline__ float fast_rcp(float x) {
    return __builtin_amdgcn_rcpf(x);
}
__device__ __forceinline__ float sigmoidf_(float x) {
    return fast_rcp(1.f + __expf(-x));
}
__device__ __forceinline__ float tanhf_fast(float x) {
    float ax = fabsf(x);
    float e  = __expf(-2.f * ax);
    float t  = (1.f - e) * fast_rcp(1.f + e);
    return copysignf(t, x);
}

// ---------- bf16 split helpers (truncation; hi+lo ~ 2^-17 rel) ----------
__device__ __forceinline__ ushort_t bf16hi(float x) {
    return (ushort_t)(__float_as_uint(x) >> 16);
}
__device__ __forceinline__ float bf16tof(ushort_t u) {
    return __uint_as_float(((uint_t)u) << 16);
}

// ---------- conv1 (1->10, 5x5 VALID) + maxpool2 + tanh ----------
// x: [B,784] as 28x28, out COMPACT: [B,144,10]
__global__ __launch_bounds__(256) void conv1_pool_tanh(
    const float* __restrict__ x, const float* __restrict__ w,
    const float* __restrict__ bias, float* __restrict__ out)
{
    __shared__ float sw[250];
    __shared__ float sb[10];
    int t = threadIdx.x;
    if (t < 250) sw[t] = w[t];
    if (t < 10)  sb[t] = bias[t];
    __syncthreads();

    int gp  = blockIdx.x * 256 + t;
    int b   = gp / 144;
    int pix = gp % 144;
    int py = pix / 12, px = pix % 12;

    const float* img = x + (long)b * 784 + (2 * py) * 28 + 2 * px;
    float r[6][6];
#pragma unroll
    for (int ry = 0; ry < 6; ++ry)
#pragma unroll
        for (int rx = 0; rx < 6; ++rx)
            r[ry][rx] = img[ry * 28 + rx];

    float* ob = out + ((long)b * 144 + pix) * 10;
    for (int oc = 0; oc < 10; ++oc) {
        float a0 = 0.f, a1 = 0.f, a2 = 0.f, a3 = 0.f;
#pragma unroll
        for (int ky = 0; ky < 5; ++ky)
#pragma unroll
            for (int kx = 0; kx < 5; ++kx) {
                float wv = sw[oc * 25 + ky * 5 + kx];
                a0 += wv * r[ky][kx];
                a1 += wv * r[ky][kx + 1];
                a2 += wv * r[ky + 1][kx];
                a3 += wv * r[ky + 1][kx + 1];
            }
        float m = fmaxf(fmaxf(a0, a1), fmaxf(a2, a3)) + sb[oc];
        ob[oc] = tanhf_fast(m);
    }
}

// ---------- MFMA 2D-LSTM ----------
// x compact [B, H*W, CIN]; Wx [5H,CIN], Whl/Whu [5H,HID], bias [5H]
// out compact [B, H*W, HID].
template<int H, int W, int HID, int CIN, int KV, int NK, int NW, int VSTR, int GSTR>
__global__ __launch_bounds__(NW * 64) void mdlstm_mfma(
    const float* __restrict__ x, const float* __restrict__ Wx,
    const float* __restrict__ Whl, const float* __restrict__ Whu,
    const float* __restrict__ bias, float* __restrict__ out)
{
    constexpr int N    = H * W;
    constexpr int NT   = NW * 64;
    constexpr int NEPI = 16 * HID;
    constexpr int HL0  = CIN, HU0 = CIN + HID;
    constexpr int NXA  = 16 * CIN;
    constexpr int NSTG = 16 * W * CIN;
    static_assert(NW * 16 >= 5 * HID, "tiles cover gate rows");
    static_assert(KV >= CIN + 2 * HID, "K covers V");
    static_assert(NEPI <= NT && NXA <= NT, "thread budget");

    __shared__ ushort_t sV[16][VSTR];
    __shared__ float    sG[16][GSTR];
    __shared__ uint_t   sHrow[W][16][HID];
    __shared__ uint_t   sXrow[2][W][16][CIN];

    const int tid  = threadIdx.x;
    const int lane = tid & 63;
    const int wid  = tid >> 6;
    const int lr   = lane & 15;
    const int lg   = lane >> 4;
    const long bB  = (long)blockIdx.x * 16;

    sh8 Ah[NK], Al[NK];
    {
        const int r = wid * 16 + lr;
#pragma unroll
        for (int ks = 0; ks < NK; ++ks) {
#pragma unroll
            for (int e = 0; e < 8; ++e) {
                int k = ks * 32 + lg * 8 + e;
                float wv = 0.f;
                if (r < 5 * HID) {
                    if (k < CIN)            wv = Wx[r * CIN + k];
                    else if (k < HL0 + HID) wv = Whl[r * HID + (k - HL0)];
                    else if (k < HU0 + HID) wv = Whu[r * HID + (k - HU0)];
                }
                ushort_t hi = bf16hi(wv);
                Ah[ks][e] = (short)hi;
                Al[ks][e] = (short)bf16hi(wv - bf16tof(hi));
            }
        }
    }
    f4 biasF;
#pragma unroll
    for (int q = 0; q < 4; ++q) {
        int rr = wid * 16 + lg * 4 + q;
        biasF[q] = (rr < 5 * HID) ? bias[rr] : 0.f;
    }

    for (int idx = tid; idx < 16 * VSTR; idx += NT) (&sV[0][0])[idx] = 0;
    for (int idx = tid; idx < W * 16 * HID; idx += NT) (&sHrow[0][0][0])[idx] = 0;

    for (int idx = tid; idx < NSTG; idx += NT) {
        int batch = idx / (W * CIN);
        int rr    = idx % (W * CIN);
        float xv  = x[(bB + batch) * (N * CIN) + rr];
        ushort_t hi = bf16hi(xv);
        ushort_t lo = bf16hi(xv - bf16tof(hi));
        sXrow[0][rr / CIN][batch][rr % CIN] = ((uint_t)hi << 16) | lo;
    }
    __syncthreads();
    if (tid < NXA) {
        int batch = tid & 15, c = tid >> 4;
        uint_t xv = sXrow[0][0][batch][c];
        sV[batch][c]      = (ushort_t)(xv >> 16);
        sV[batch][KV + c] = (ushort_t)(xv & 0xffff);
    }
    __syncthreads();

    const int batch_e = tid & 15, j_e = tid >> 4;
    float c_row[W];
#pragma unroll
    for (int q = 0; q < W; ++q) c_row[q] = 0.f;

    for (int i = 0; i < H; ++i) {
        float c_left = 0.f;
#pragma unroll
        for (int jc = 0; jc < W; ++jc) {
            {
                sh8 Bh[NK];
#pragma unroll
                for (int ks = 0; ks < NK; ++ks)
                    Bh[ks] = *(const sh8*)&sV[lr][ks * 32 + lg * 8];
                f4 acc = __builtin_amdgcn_mfma_f32_16x16x32_bf16(
                             Ah[0], Bh[0], biasF, 0, 0, 0);
#pragma unroll
                for (int ks = 1; ks < NK; ++ks)
                    acc = __builtin_amdgcn_mfma_f32_16x16x32_bf16(
                              Ah[ks], Bh[ks], acc, 0, 0, 0);
#pragma unroll
                for (int ks = 0; ks < NK; ++ks) {
                    sh8 Bl = *(const sh8*)&sV[lr][KV + ks * 32 + lg * 8];
                    acc = __builtin_amdgcn_mfma_f32_16x16x32_bf16(
                              Ah[ks], Bl, acc, 0, 0, 0);
                }
#pragma unroll
                for (int ks = 0; ks < NK; ++ks)
                    acc = __builtin_amdgcn_mfma_f32_16x16x32_bf16(
                              Al[ks], Bh[ks], acc, 0, 0, 0);
                *(f4*)&sG[lr][wid * 16 + lg * 4] = acc;
            }
            if (jc == 0 && i + 1 < H) {
                const int nb = (i + 1) & 1;
                for (int idx = tid; idx < NSTG; idx += NT) {
                    int batch = idx / (W * CIN);
                    int rr    = idx % (W * CIN);
                    float xv  = x[(bB + batch) * (N * CIN) + (i + 1) * (W * CIN) + rr];
                    ushort_t hi = bf16hi(xv);
                    ushort_t lo = bf16hi(xv - bf16tof(hi));
                    sXrow[nb][rr / CIN][batch][rr % CIN] = ((uint_t)hi << 16) | lo;
                }
            }
            __syncthreads();
            if (tid < NEPI) {
                float g[5];
#pragma unroll
                for (int p = 0; p < 5; ++p) g[p] = sG[batch_e][j_e + HID * p];
                float ig  = sigmoidf_(g[0]), f1g = sigmoidf_(g[1]);
                float f2g = sigmoidf_(g[2]), og  = sigmoidf_(g[3]);
                float gg  = tanhf_fast(g[4]);
                float cc  = f1g * c_left + f2g * c_row[jc] + ig * gg;
                float hh  = og * tanhf_fast(cc);
                c_row[jc] = cc;
                c_left    = cc;
                ushort_t hhi = bf16hi(hh);
                ushort_t hlo = bf16hi(hh - bf16tof(hhi));
                if (jc < W - 1) {
                    sV[batch_e][HL0 + j_e]      = hhi;
                    sV[batch_e][KV + HL0 + j_e] = hlo;
                }
                sHrow[jc][batch_e][j_e] = ((uint_t)hhi << 16) | hlo;
                out[(bB + batch_e) * (long)(N * HID) + (i * W + jc) * HID + j_e] = hh;
            }
            if (i * W + jc < H * W - 1) {
                const int jc2 = (jc == W - 1) ? 0 : jc + 1;
                const int ib  = (jc == W - 1) ? ((i + 1) & 1) : (i & 1);
                if (tid >= NT - NEPI) {
                    int t2 = tid - (NT - NEPI);
                    int batch = t2 & 15, j2 = t2 >> 4;
                    uint_t hv = sHrow[jc2][batch][j2];
                    sV[batch][HU0 + j2]      = (ushort_t)(hv >> 16);
                    sV[batch][KV + HU0 + j2] = (ushort_t)(hv & 0xffff);
                }
                if (tid < NXA) {
                    int batch = tid & 15, c = tid >> 4;
                    uint_t xv = sXrow[ib][jc2][batch][c];
                    sV[batch][c]      = (ushort_t)(xv >> 16);
                    sV[batch][KV + c] = (ushort_t)(xv & 0xffff);
                }
                if (jc == W - 1 && tid < NEPI) {
                    sV[batch_e][HL0 + j_e]      = 0;
                    sV[batch_e][KV + HL0 + j_e] = 0;
                }
            }
            __syncthreads();
        }
    }
}

// ---------- conv2 via tap-decomposed MFMA (atomic-free reduction) ----------
// in COMPACT [B,144,20] fp32; wt [30,20,5,5]; out COMPACT [B,16,30].
// Block = 1 image, 5 waves; wave wid = tx. Per tx: GEMM over k=(ty,ic):
// O[oc][n] += W[oc][ty,ic,tx] * I[ty,ic][pos(n)+ty*12+tx].  bf16 hi/lo split,
// 3 independent 5-MFMA chains per (m-tile). Cross-wave reduction via plain
// ds_write_b128 partial slots + tree sum (NO atomics).
__global__ __launch_bounds__(320) void conv2_mfma(
    const float* __restrict__ in, const float* __restrict__ wt,
    const float* __restrict__ bias, float* __restrict__ out)
{
    __shared__ ushort_t sHi[144][40];        // img bf16 hi (k 0..19 real, 20..31 zero)
    __shared__ ushort_t sLo[144][40];        // img bf16 lo
    __shared__ float    sPart[5][2][4][16][20]; // [wave][m][p][c][row(16)+pad]
    __shared__ float    sB[30];

    const int tid  = threadIdx.x;
    const int lane = tid & 63;
    const int wid  = tid >> 6;          // = tx
    const int c    = lane & 15;         // A: M-row ; B/C: col (pixel-in-tile)
    const int kg   = lane >> 4;         // k-group / C row-group
    const long b   = blockIdx.x;

    // ---- A-frags in registers: Ah/Al[ty][m-tile] ----
    sh8 Ah[5][2], Al[5][2];
#pragma unroll
    for (int ks = 0; ks < 5; ++ks) {
#pragma unroll
        for (int m = 0; m < 2; ++m) {
#pragma unroll
            for (int e = 0; e < 8; ++e) {
                int ic = kg * 8 + e;
                int oc = m * 16 + c;
                float wv = (ic < 20 && oc < 30)
                         ? wt[((oc * 20 + ic) * 5 + ks) * 5 + wid] : 0.f;
                ushort_t hi = bf16hi(wv);
                Ah[ks][m][e] = (short)hi;
                Al[ks][m][e] = (short)bf16hi(wv - bf16tof(hi));
            }
        }
    }

    // ---- stage image (bf16 split, zero-padded k) ----
    for (int idx = tid; idx < 144 * 40; idx += 320) {
        int pos = idx / 40, s = idx % 40;
        float v = (s < 20) ? in[b * 2880 + pos * 20 + s] : 0.f;
        ushort_t hi = bf16hi(v);
        sHi[pos][s] = hi;
        sLo[pos][s] = bf16hi(v - bf16tof(hi));
    }
    if (tid < 30) sB[tid] = bias[tid];
    __syncthreads();

    // ---- main: 4 pixel tiles; 6 independent MFMA chains each ----
    const int y0 = c >> 3, x = c & 7;   // conv pixel within tile: n = p*16+c
#pragma unroll
    for (int p = 0; p < 4; ++p) {
        const int pos = (2 * p + y0) * 12 + x + wid;
        const ushort_t* bh = &sHi[pos][kg * 8];
        const ushort_t* bl = &sLo[pos][kg * 8];
        f4 hh0 = {0.f,0.f,0.f,0.f}, hl0 = {0.f,0.f,0.f,0.f}, lh0 = {0.f,0.f,0.f,0.f};
        f4 hh1 = {0.f,0.f,0.f,0.f}, hl1 = {0.f,0.f,0.f,0.f}, lh1 = {0.f,0.f,0.f,0.f};
#pragma unroll
        for (int ks = 0; ks < 5; ++ks) {
            sh8 Bh = *(const sh8*)(bh + ks * 12 * 40);
            sh8 Bl = *(const sh8*)(bl + ks * 12 * 40);
            hh0 = __builtin_amdgcn_mfma_f32_16x16x32_bf16(Ah[ks][0], Bh, hh0, 0, 0, 0);
            hl0 = __builtin_amdgcn_mfma_f32_16x16x32_bf16(Ah[ks][0], Bl, hl0, 0, 0, 0);
            lh0 = __builtin_amdgcn_mfma_f32_16x16x32_bf16(Al[ks][0], Bh, lh0, 0, 0, 0);
            hh1 = __builtin_amdgcn_mfma_f32_16x16x32_bf16(Ah[ks][1], Bh, hh1, 0, 0, 0);
            hl1 = __builtin_amdgcn_mfma_f32_16x16x32_bf16(Ah[ks][1], Bl, hl1, 0, 0, 0);
            lh1 = __builtin_amdgcn_mfma_f32_16x16x32_bf16(Al[ks][1], Bh, lh1, 0, 0, 0);
        }
        f4 c0 = hh0 + hl0 + lh0;
        f4 c1 = hh1 + hl1 + lh1;
        *(f4*)&sPart[wid][0][p][c][kg * 4] = c0;
        *(f4*)&sPart[wid][1][p][c][kg * 4] = c1;
    }
    __syncthreads();

    // ---- tree-sum 5 wave partials (512 f4 items over 320 threads) ----
    for (int idx = tid; idx < 512; idx += 320) {
        int kk = idx & 3;
        int cc = (idx >> 2) & 15;
        int pp = (idx >> 6) & 3;
        int mm = idx >> 8;
        f4 s = *(const f4*)&sPart[0][mm][pp][cc][kk * 4];
#pragma unroll
        for (int w = 1; w < 5; ++w)
            s += *(const f4*)&sPart[w][mm][pp][cc][kk * 4];
        *(f4*)&sPart[0][mm][pp][cc][kk * 4] = s;
    }
    __syncthreads();

    // ---- epilogue: bias + 2x2 maxpool + tanh, compact store [B,16,30] ----
    for (int idx = tid; idx < 480; idx += 320) {
        int pix = idx / 30, oc = idx % 30;
        int m = oc >> 4, r = oc & 15;
        int py = pix >> 2, px = pix & 3;
        float v = -1e30f;
#pragma unroll
        for (int dy = 0; dy < 2; ++dy)
#pragma unroll
            for (int dx = 0; dx < 2; ++dx) {
                int n = (2 * py + dy) * 8 + 2 * px + dx;
                v = fmaxf(v, sPart[0][m][n >> 4][n & 15][r]);
            }
        out[b * 480 + idx] = tanhf_fast(v + sB[oc]);
    }
}

// ---------- fc1 (640->100) + tanh ----------
// in COMPACT [B,16,40] (k' = pix*40+hid); w [100,640] with k = hid*16+pix.
__global__ __launch_bounds__(256) void fc1_tanh(
    const float* __restrict__ in, const float* __restrict__ w,
    const float* __restrict__ bias, float* __restrict__ out)
{
    int t = threadIdx.x;
    int bblk = blockIdx.x & 15;
    int o    = blockIdx.x >> 4;
    long b = (long)bblk * 256 + t;
    const float* wr = w + o * 640;
    const float* xr = in + b * 640;
    float acc = 0.f;
#pragma unroll 4
    for (int pix = 0; pix < 16; ++pix) {
        const float* xp = xr + pix * 40;
#pragma unroll
        for (int hid = 0; hid < 40; hid += 4) {
            float4 xv = *(const float4*)(xp + hid);
            acc += wr[(hid + 0) * 16 + pix] * xv.x
                 + wr[(hid + 1) * 16 + pix] * xv.y
                 + wr[(hid + 2) * 16 + pix] * xv.z
                 + wr[(hid + 3) * 16 + pix] * xv.w;
        }
    }
    out[b * 100 + o] = tanhf_fast(acc + bias[o]);
}

// ---------- fc2 (100->10) + softmax ----------
__global__ __launch_bounds__(64) void fc2_softmax(
    const float* __restrict__ in, const float* __restrict__ w,
    const float* __restrict__ bias, float* __restrict__ out)
{
    long b = (long)blockIdx.x * 64 + threadIdx.x;
    const float* xr = in + b * 100;
    float logit[10];
#pragma unroll
    for (int o = 0; o < 10; ++o) logit[o] = bias[o];
    for (int k = 0; k < 100; ++k) {
        float xv = xr[k];
#pragma unroll
        for (int o = 0; o < 10; ++o) logit[o] += xv * w[o * 100 + k];
    }
    float m = logit[0];
#pragma unroll
    for (int o = 1; o < 10; ++o) m = fmaxf(m, logit[o]);
    float s = 0.f;
#pragma unroll
    for (int o = 0; o < 10; ++o) { logit[o] = __expf(logit[o] - m); s += logit[o]; }
    float inv = fast_rcp(s);
#pragma unroll
    for (int o = 0; o < 10; ++o) out[b * 10 + o] = logit[o] * inv;
}

extern "C" void kernel_launch(void* const* d_in, const int* in_sizes, int n_in,
                              void* d_out, int out_size, void* d_ws, size_t ws_size,
                              hipStream_t stream)
{
    const float* x    = (const float*)d_in[0];
    const float* c1w  = (const float*)d_in[1];
    const float* c1b  = (const float*)d_in[2];
    const float* m1Wx = (const float*)d_in[3];
    const float* m1Wl = (const float*)d_in[4];
    const float* m1Wu = (const float*)d_in[5];
    const float* m1b  = (const float*)d_in[6];
    const float* c2w  = (const float*)d_in[7];
    const float* c2b  = (const float*)d_in[8];
    const float* m2Wx = (const float*)d_in[9];
    const float* m2Wl = (const float*)d_in[10];
    const float* m2Wu = (const float*)d_in[11];
    const float* m2b  = (const float*)d_in[12];
    const float* f1w  = (const float*)d_in[13];
    const float* f1b  = (const float*)d_in[14];
    const float* f2w  = (const float*)d_in[15];
    const float* f2b  = (const float*)d_in[16];
    float* outp = (float*)d_out;

    char* ws = (char*)d_ws;
    float* a1 = (float*)ws;                 // [B,144,10] 23.6 MB
    float* h1 = (float*)(ws + 23592960);    // [B,144,20] 47.2 MB
    float* a2 = a1;                         // [B,16,30] reuse
    float* h2 = h1;                         // [B,16,40] reuse
    float* f1 = a1;                         // [B,100]   reuse

    conv1_pool_tanh<<<2304, 256, 0, stream>>>(x, c1w, c1b, a1);
    // m1: V=[x10|hl20|hu20] pad KV=64, NK=2, 7 M-tiles (112 rows)
    mdlstm_mfma<12, 12, 20, 10, 64, 2, 7, 136, 116><<<256, 448, 0, stream>>>(
        a1, m1Wx, m1Wl, m1Wu, m1b, h1);
    conv2_mfma<<<4096, 320, 0, stream>>>(h1, c2w, c2b, a2);
    // m2: V=[x30|hl40|hu40] pad KV=128, NK=4, 13 M-tiles (208 rows)
    mdlstm_mfma<4, 4, 40, 30, 128, 4, 13, 264, 212><<<256, 832, 0, stream>>>(
        a2, m2Wx, m2Wl, m2Wu, m2b, h2);
    fc1_tanh<<<1600, 256, 0, stream>>>(h2, f1w, f1b, f1);
    fc2_softmax<<<64, 64, 0, stream>>>(f1, f2w, f2b, outp);
}

// Round 6
// 451.576 us; speedup vs baseline: 1.5719x; 1.1594x over previous
//
#include <hip/hip_runtime.h>
#include <hip/hip_bf16.h>

typedef __attribute__((ext_vector_type(8))) short sh8;
typedef __attribute__((ext_vector_type(4))) float f4;
typedef unsigned short ushort_t;
typedef unsigned int uint_t;

// ---------- fast transcendentals (fp32) ----------
__device__ __forceinline__ float fast_rcp(float x) {
    return __builtin_amdgcn_rcpf(x);
}
__device__ __forceinline__ float sigmoidf_(float x) {
    return fast_rcp(1.f + __expf(-x));
}
__device__ __forceinline__ float tanhf_fast(float x) {
    float ax = fabsf(x);
    float e  = __expf(-2.f * ax);
    float t  = (1.f - e) * fast_rcp(1.f + e);
    return copysignf(t, x);
}

// ---------- bf16 split helpers (truncation; hi+lo ~ 2^-17 rel) ----------
__device__ __forceinline__ ushort_t bf16hi(float x) {
    return (ushort_t)(__float_as_uint(x) >> 16);
}
__device__ __forceinline__ float bf16tof(ushort_t u) {
    return __uint_as_float(((uint_t)u) << 16);
}

// ---------- conv1 (1->10, 5x5 VALID) + maxpool2 + tanh ----------
// x: [B,784] as 28x28, out COMPACT: [B,144,10]
__global__ __launch_bounds__(256) void conv1_pool_tanh(
    const float* __restrict__ x, const float* __restrict__ w,
    const float* __restrict__ bias, float* __restrict__ out)
{
    __shared__ float sw[250];
    __shared__ float sb[10];
    int t = threadIdx.x;
    if (t < 250) sw[t] = w[t];
    if (t < 10)  sb[t] = bias[t];
    __syncthreads();

    int gp  = blockIdx.x * 256 + t;
    int b   = gp / 144;
    int pix = gp % 144;
    int py = pix / 12, px = pix % 12;

    const float* img = x + (long)b * 784 + (2 * py) * 28 + 2 * px;
    float r[6][6];
#pragma unroll
    for (int ry = 0; ry < 6; ++ry)
#pragma unroll
        for (int rx = 0; rx < 6; ++rx)
            r[ry][rx] = img[ry * 28 + rx];

    float* ob = out + ((long)b * 144 + pix) * 10;
    for (int oc = 0; oc < 10; ++oc) {
        float a0 = 0.f, a1 = 0.f, a2 = 0.f, a3 = 0.f;
#pragma unroll
        for (int ky = 0; ky < 5; ++ky)
#pragma unroll
            for (int kx = 0; kx < 5; ++kx) {
                float wv = sw[oc * 25 + ky * 5 + kx];
                a0 += wv * r[ky][kx];
                a1 += wv * r[ky][kx + 1];
                a2 += wv * r[ky + 1][kx];
                a3 += wv * r[ky + 1][kx + 1];
            }
        float m = fmaxf(fmaxf(a0, a1), fmaxf(a2, a3)) + sb[oc];
        ob[oc] = tanhf_fast(m);
    }
}

// ---------- MFMA 2D-LSTM ----------
// x compact [B, H*W, CIN]; Wx [5H,CIN], Whl/Whu [5H,HID], bias [5H]
// out compact [B, H*W, HID].
template<int H, int W, int HID, int CIN, int KV, int NK, int NW, int VSTR, int GSTR>
__global__ __launch_bounds__(NW * 64) void mdlstm_mfma(
    const float* __restrict__ x, const float* __restrict__ Wx,
    const float* __restrict__ Whl, const float* __restrict__ Whu,
    const float* __restrict__ bias, float* __restrict__ out)
{
    constexpr int N    = H * W;
    constexpr int NT   = NW * 64;
    constexpr int NEPI = 16 * HID;
    constexpr int HL0  = CIN, HU0 = CIN + HID;
    constexpr int NXA  = 16 * CIN;
    constexpr int NSTG = 16 * W * CIN;
    static_assert(NW * 16 >= 5 * HID, "tiles cover gate rows");
    static_assert(KV >= CIN + 2 * HID, "K covers V");
    static_assert(NEPI <= NT && NXA <= NT, "thread budget");

    __shared__ ushort_t sV[16][VSTR];
    __shared__ float    sG[16][GSTR];
    __shared__ uint_t   sHrow[W][16][HID];
    __shared__ uint_t   sXrow[2][W][16][CIN];

    const int tid  = threadIdx.x;
    const int lane = tid & 63;
    const int wid  = tid >> 6;
    const int lr   = lane & 15;
    const int lg   = lane >> 4;
    const long bB  = (long)blockIdx.x * 16;

    sh8 Ah[NK], Al[NK];
    {
        const int r = wid * 16 + lr;
#pragma unroll
        for (int ks = 0; ks < NK; ++ks) {
#pragma unroll
            for (int e = 0; e < 8; ++e) {
                int k = ks * 32 + lg * 8 + e;
                float wv = 0.f;
                if (r < 5 * HID) {
                    if (k < CIN)            wv = Wx[r * CIN + k];
                    else if (k < HL0 + HID) wv = Whl[r * HID + (k - HL0)];
                    else if (k < HU0 + HID) wv = Whu[r * HID + (k - HU0)];
                }
                ushort_t hi = bf16hi(wv);
                Ah[ks][e] = (short)hi;
                Al[ks][e] = (short)bf16hi(wv - bf16tof(hi));
            }
        }
    }
    f4 biasF;
#pragma unroll
    for (int q = 0; q < 4; ++q) {
        int rr = wid * 16 + lg * 4 + q;
        biasF[q] = (rr < 5 * HID) ? bias[rr] : 0.f;
    }

    for (int idx = tid; idx < 16 * VSTR; idx += NT) (&sV[0][0])[idx] = 0;
    for (int idx = tid; idx < W * 16 * HID; idx += NT) (&sHrow[0][0][0])[idx] = 0;

    for (int idx = tid; idx < NSTG; idx += NT) {
        int batch = idx / (W * CIN);
        int rr    = idx % (W * CIN);
        float xv  = x[(bB + batch) * (N * CIN) + rr];
        ushort_t hi = bf16hi(xv);
        ushort_t lo = bf16hi(xv - bf16tof(hi));
        sXrow[0][rr / CIN][batch][rr % CIN] = ((uint_t)hi << 16) | lo;
    }
    __syncthreads();
    if (tid < NXA) {
        int batch = tid & 15, c = tid >> 4;
        uint_t xv = sXrow[0][0][batch][c];
        sV[batch][c]      = (ushort_t)(xv >> 16);
        sV[batch][KV + c] = (ushort_t)(xv & 0xffff);
    }
    __syncthreads();

    const int batch_e = tid & 15, j_e = tid >> 4;
    float c_row[W];
#pragma unroll
    for (int q = 0; q < W; ++q) c_row[q] = 0.f;

    for (int i = 0; i < H; ++i) {
        float c_left = 0.f;
#pragma unroll
        for (int jc = 0; jc < W; ++jc) {
            {
                sh8 Bh[NK];
#pragma unroll
                for (int ks = 0; ks < NK; ++ks)
                    Bh[ks] = *(const sh8*)&sV[lr][ks * 32 + lg * 8];
                f4 acc = __builtin_amdgcn_mfma_f32_16x16x32_bf16(
                             Ah[0], Bh[0], biasF, 0, 0, 0);
#pragma unroll
                for (int ks = 1; ks < NK; ++ks)
                    acc = __builtin_amdgcn_mfma_f32_16x16x32_bf16(
                              Ah[ks], Bh[ks], acc, 0, 0, 0);
#pragma unroll
                for (int ks = 0; ks < NK; ++ks) {
                    sh8 Bl = *(const sh8*)&sV[lr][KV + ks * 32 + lg * 8];
                    acc = __builtin_amdgcn_mfma_f32_16x16x32_bf16(
                              Ah[ks], Bl, acc, 0, 0, 0);
                }
#pragma unroll
                for (int ks = 0; ks < NK; ++ks)
                    acc = __builtin_amdgcn_mfma_f32_16x16x32_bf16(
                              Al[ks], Bh[ks], acc, 0, 0, 0);
                *(f4*)&sG[lr][wid * 16 + lg * 4] = acc;
            }
            if (jc == 0 && i + 1 < H) {
                const int nb = (i + 1) & 1;
                for (int idx = tid; idx < NSTG; idx += NT) {
                    int batch = idx / (W * CIN);
                    int rr    = idx % (W * CIN);
                    float xv  = x[(bB + batch) * (N * CIN) + (i + 1) * (W * CIN) + rr];
                    ushort_t hi = bf16hi(xv);
                    ushort_t lo = bf16hi(xv - bf16tof(hi));
                    sXrow[nb][rr / CIN][batch][rr % CIN] = ((uint_t)hi << 16) | lo;
                }
            }
            __syncthreads();
            if (tid < NEPI) {
                float g[5];
#pragma unroll
                for (int p = 0; p < 5; ++p) g[p] = sG[batch_e][j_e + HID * p];
                float ig  = sigmoidf_(g[0]), f1g = sigmoidf_(g[1]);
                float f2g = sigmoidf_(g[2]), og  = sigmoidf_(g[3]);
                float gg  = tanhf_fast(g[4]);
                float cc  = f1g * c_left + f2g * c_row[jc] + ig * gg;
                float hh  = og * tanhf_fast(cc);
                c_row[jc] = cc;
                c_left    = cc;
                ushort_t hhi = bf16hi(hh);
                ushort_t hlo = bf16hi(hh - bf16tof(hhi));
                if (jc < W - 1) {
                    sV[batch_e][HL0 + j_e]      = hhi;
                    sV[batch_e][KV + HL0 + j_e] = hlo;
                }
                sHrow[jc][batch_e][j_e] = ((uint_t)hhi << 16) | hlo;
                out[(bB + batch_e) * (long)(N * HID) + (i * W + jc) * HID + j_e] = hh;
            }
            if (i * W + jc < H * W - 1) {
                const int jc2 = (jc == W - 1) ? 0 : jc + 1;
                const int ib  = (jc == W - 1) ? ((i + 1) & 1) : (i & 1);
                if (tid >= NT - NEPI) {
                    int t2 = tid - (NT - NEPI);
                    int batch = t2 & 15, j2 = t2 >> 4;
                    uint_t hv = sHrow[jc2][batch][j2];
                    sV[batch][HU0 + j2]      = (ushort_t)(hv >> 16);
                    sV[batch][KV + HU0 + j2] = (ushort_t)(hv & 0xffff);
                }
                if (tid < NXA) {
                    int batch = tid & 15, c = tid >> 4;
                    uint_t xv = sXrow[ib][jc2][batch][c];
                    sV[batch][c]      = (ushort_t)(xv >> 16);
                    sV[batch][KV + c] = (ushort_t)(xv & 0xffff);
                }
                if (jc == W - 1 && tid < NEPI) {
                    sV[batch_e][HL0 + j_e]      = 0;
                    sV[batch_e][KV + HL0 + j_e] = 0;
                }
            }
            __syncthreads();
        }
    }
}

// ---------- prep: scatter conv2 weights into MFMA A-fragment layout ----------
// wt [30,20,5,5] -> wf shorts, sh8 index = (((tx*5+ty)*2+m)*2+h)*64 + lane,
// element e; lane=(kg*16+c), oc=m*16+c, ic=kg*8+e. h=0 hi, h=1 lo.
__global__ __launch_bounds__(256) void prep_conv2_frags(
    const float* __restrict__ wt, short* __restrict__ wf)
{
    int id = blockIdx.x * 256 + threadIdx.x;   // over 25*2*64*8 = 25600
    if (id >= 25600) return;
    int e    = id & 7;
    int lane = (id >> 3) & 63;
    int m    = (id >> 9) & 1;
    int tt   = id >> 10;            // tx*5+ty
    int tx = tt / 5, ty = tt % 5;
    int c = lane & 15, kg = lane >> 4;
    int oc = m * 16 + c, ic = kg * 8 + e;
    float wv = (oc < 30 && ic < 20) ? wt[((oc * 20 + ic) * 5 + ty) * 5 + tx] : 0.f;
    ushort_t hi = bf16hi(wv);
    ushort_t lo = bf16hi(wv - bf16tof(hi));
    wf[(((tt * 2 + m) * 2 + 0) * 64 + lane) * 8 + e] = (short)hi;
    wf[(((tt * 2 + m) * 2 + 1) * 64 + lane) * 8 + e] = (short)lo;
}

// ---------- conv2 via tap-decomposed MFMA (frag weights precomputed) ----------
// in COMPACT [B,144,20] fp32; wf frag-layout weights; out COMPACT [B,16,30].
// Block = 1 image, 5 waves; wave wid = tx. Per tx: GEMM over k=(ty,ic):
// O[oc][n] += W[oc][ty,ic,tx] * I[ty,ic][pos(n)+ty*12+tx].  bf16 hi/lo split,
// 3 independent 5-MFMA chains per m-tile; ds_write partials + tree sum.
__global__ __launch_bounds__(320) void conv2_mfma(
    const float* __restrict__ in, const short* __restrict__ wf,
    const float* __restrict__ bias, float* __restrict__ out)
{
    __shared__ ushort_t sHi[144][40];        // img bf16 hi (k 0..19 real, 20..31 zero)
    __shared__ ushort_t sLo[144][40];        // img bf16 lo
    __shared__ float    sPart[5][2][4][16][20]; // [wave][m][p][c][row(16)+pad]
    __shared__ float    sB[30];

    const int tid  = threadIdx.x;
    const int lane = tid & 63;
    const int wid  = tid >> 6;          // = tx
    const int c    = lane & 15;         // A: M-row ; B/C: col (pixel-in-tile)
    const int kg   = lane >> 4;         // k-group / C row-group
    const long b   = blockIdx.x;

    // ---- A-frags: coalesced loads from frag-layout global buffer ----
    const sh8* wfv = (const sh8*)wf;
    sh8 Ah[5][2], Al[5][2];
#pragma unroll
    for (int ty = 0; ty < 5; ++ty)
#pragma unroll
        for (int m = 0; m < 2; ++m) {
            int base = (((wid * 5 + ty) * 2 + m) * 2) * 64 + lane;
            Ah[ty][m] = wfv[base];
            Al[ty][m] = wfv[base + 64];
        }

    // ---- stage image (bf16 split, zero-padded k) ----
    for (int idx = tid; idx < 144 * 40; idx += 320) {
        int pos = idx / 40, s = idx % 40;
        float v = (s < 20) ? in[b * 2880 + pos * 20 + s] : 0.f;
        ushort_t hi = bf16hi(v);
        sHi[pos][s] = hi;
        sLo[pos][s] = bf16hi(v - bf16tof(hi));
    }
    if (tid < 30) sB[tid] = bias[tid];
    __syncthreads();

    // ---- main: 4 pixel tiles; 6 independent MFMA chains each ----
    const int y0 = c >> 3, x = c & 7;   // conv pixel within tile: n = p*16+c
#pragma unroll
    for (int p = 0; p < 4; ++p) {
        const int pos = (2 * p + y0) * 12 + x + wid;
        const ushort_t* bh = &sHi[pos][kg * 8];
        const ushort_t* bl = &sLo[pos][kg * 8];
        f4 hh0 = {0.f,0.f,0.f,0.f}, hl0 = {0.f,0.f,0.f,0.f}, lh0 = {0.f,0.f,0.f,0.f};
        f4 hh1 = {0.f,0.f,0.f,0.f}, hl1 = {0.f,0.f,0.f,0.f}, lh1 = {0.f,0.f,0.f,0.f};
#pragma unroll
        for (int ks = 0; ks < 5; ++ks) {
            sh8 Bh = *(const sh8*)(bh + ks * 12 * 40);
            sh8 Bl = *(const sh8*)(bl + ks * 12 * 40);
            hh0 = __builtin_amdgcn_mfma_f32_16x16x32_bf16(Ah[ks][0], Bh, hh0, 0, 0, 0);
            hl0 = __builtin_amdgcn_mfma_f32_16x16x32_bf16(Ah[ks][0], Bl, hl0, 0, 0, 0);
            lh0 = __builtin_amdgcn_mfma_f32_16x16x32_bf16(Al[ks][0], Bh, lh0, 0, 0, 0);
            hh1 = __builtin_amdgcn_mfma_f32_16x16x32_bf16(Ah[ks][1], Bh, hh1, 0, 0, 0);
            hl1 = __builtin_amdgcn_mfma_f32_16x16x32_bf16(Ah[ks][1], Bl, hl1, 0, 0, 0);
            lh1 = __builtin_amdgcn_mfma_f32_16x16x32_bf16(Al[ks][1], Bh, lh1, 0, 0, 0);
        }
        f4 c0 = hh0 + hl0 + lh0;
        f4 c1 = hh1 + hl1 + lh1;
        *(f4*)&sPart[wid][0][p][c][kg * 4] = c0;
        *(f4*)&sPart[wid][1][p][c][kg * 4] = c1;
    }
    __syncthreads();

    // ---- tree-sum 5 wave partials (512 f4 items over 320 threads) ----
    for (int idx = tid; idx < 512; idx += 320) {
        int kk = idx & 3;
        int cc = (idx >> 2) & 15;
        int pp = (idx >> 6) & 3;
        int mm = idx >> 8;
        f4 s = *(const f4*)&sPart[0][mm][pp][cc][kk * 4];
#pragma unroll
        for (int w = 1; w < 5; ++w)
            s += *(const f4*)&sPart[w][mm][pp][cc][kk * 4];
        *(f4*)&sPart[0][mm][pp][cc][kk * 4] = s;
    }
    __syncthreads();

    // ---- epilogue: bias + 2x2 maxpool + tanh, compact store [B,16,30] ----
    for (int idx = tid; idx < 480; idx += 320) {
        int pix = idx / 30, oc = idx % 30;
        int m = oc >> 4, r = oc & 15;
        int py = pix >> 2, px = pix & 3;
        float v = -1e30f;
#pragma unroll
        for (int dy = 0; dy < 2; ++dy)
#pragma unroll
            for (int dx = 0; dx < 2; ++dx) {
                int n = (2 * py + dy) * 8 + 2 * px + dx;
                v = fmaxf(v, sPart[0][m][n >> 4][n & 15][r]);
            }
        out[b * 480 + idx] = tanhf_fast(v + sB[oc]);
    }
}

// ---------- fc1 (640->100) + tanh ----------
// in COMPACT [B,16,40] (k' = pix*40+hid); w [100,640] with k = hid*16+pix.
__global__ __launch_bounds__(256) void fc1_tanh(
    const float* __restrict__ in, const float* __restrict__ w,
    const float* __restrict__ bias, float* __restrict__ out)
{
    int t = threadIdx.x;
    int bblk = blockIdx.x & 15;
    int o    = blockIdx.x >> 4;
    long b = (long)bblk * 256 + t;
    const float* wr = w + o * 640;
    const float* xr = in + b * 640;
    float acc = 0.f;
#pragma unroll 4
    for (int pix = 0; pix < 16; ++pix) {
        const float* xp = xr + pix * 40;
#pragma unroll
        for (int hid = 0; hid < 40; hid += 4) {
            float4 xv = *(const float4*)(xp + hid);
            acc += wr[(hid + 0) * 16 + pix] * xv.x
                 + wr[(hid + 1) * 16 + pix] * xv.y
                 + wr[(hid + 2) * 16 + pix] * xv.z
                 + wr[(hid + 3) * 16 + pix] * xv.w;
        }
    }
    out[b * 100 + o] = tanhf_fast(acc + bias[o]);
}

// ---------- fc2 (100->10) + softmax ----------
__global__ __launch_bounds__(64) void fc2_softmax(
    const float* __restrict__ in, const float* __restrict__ w,
    const float* __restrict__ bias, float* __restrict__ out)
{
    long b = (long)blockIdx.x * 64 + threadIdx.x;
    const float* xr = in + b * 100;
    float logit[10];
#pragma unroll
    for (int o = 0; o < 10; ++o) logit[o] = bias[o];
    for (int k = 0; k < 100; ++k) {
        float xv = xr[k];
#pragma unroll
        for (int o = 0; o < 10; ++o) logit[o] += xv * w[o * 100 + k];
    }
    float m = logit[0];
#pragma unroll
    for (int o = 1; o < 10; ++o) m = fmaxf(m, logit[o]);
    float s = 0.f;
#pragma unroll
    for (int o = 0; o < 10; ++o) { logit[o] = __expf(logit[o] - m); s += logit[o]; }
    float inv = fast_rcp(s);
#pragma unroll
    for (int o = 0; o < 10; ++o) out[b * 10 + o] = logit[o] * inv;
}

extern "C" void kernel_launch(void* const* d_in, const int* in_sizes, int n_in,
                              void* d_out, int out_size, void* d_ws, size_t ws_size,
                              hipStream_t stream)
{
    const float* x    = (const float*)d_in[0];
    const float* c1w  = (const float*)d_in[1];
    const float* c1b  = (const float*)d_in[2];
    const float* m1Wx = (const float*)d_in[3];
    const float* m1Wl = (const float*)d_in[4];
    const float* m1Wu = (const float*)d_in[5];
    const float* m1b  = (const float*)d_in[6];
    const float* c2w  = (const float*)d_in[7];
    const float* c2b  = (const float*)d_in[8];
    const float* m2Wx = (const float*)d_in[9];
    const float* m2Wl = (const float*)d_in[10];
    const float* m2Wu = (const float*)d_in[11];
    const float* m2b  = (const float*)d_in[12];
    const float* f1w  = (const float*)d_in[13];
    const float* f1b  = (const float*)d_in[14];
    const float* f2w  = (const float*)d_in[15];
    const float* f2b  = (const float*)d_in[16];
    float* outp = (float*)d_out;

    char* ws = (char*)d_ws;
    float* a1 = (float*)ws;                 // [B,144,10] 23.6 MB
    float* h1 = (float*)(ws + 23592960);    // [B,144,20] 47.2 MB
    float* a2 = a1;                         // [B,16,30] 7.86 MB (reuse a1)
    short* wfrag = (short*)(ws + 8388608);  // 102 KB, inside dead a1 region (>a2)
    float* h2 = h1;                         // [B,16,40] reuse
    float* f1 = a1;                         // [B,100]   reuse

    conv1_pool_tanh<<<2304, 256, 0, stream>>>(x, c1w, c1b, a1);
    // m1: V=[x10|hl20|hu20] pad KV=64, NK=2, 7 M-tiles (112 rows)
    mdlstm_mfma<12, 12, 20, 10, 64, 2, 7, 136, 116><<<256, 448, 0, stream>>>(
        a1, m1Wx, m1Wl, m1Wu, m1b, h1);
    prep_conv2_frags<<<100, 256, 0, stream>>>(c2w, wfrag);   // a1 dead now
    conv2_mfma<<<4096, 320, 0, stream>>>(h1, wfrag, c2b, a2);
    // m2: V=[x30|hl40|hu40] pad KV=128, NK=4, 13 M-tiles (208 rows)
    mdlstm_mfma<4, 4, 40, 30, 128, 4, 13, 264, 212><<<256, 832, 0, stream>>>(
        a2, m2Wx, m2Wl, m2Wu, m2b, h2);
    fc1_tanh<<<1600, 256, 0, stream>>>(h2, f1w, f1b, f1);
    fc2_softmax<<<64, 64, 0, stream>>>(f1, f2w, f2b, outp);
}

// Round 7
// 354.205 us; speedup vs baseline: 2.0040x; 1.2749x over previous
//
#include <hip/hip_runtime.h>
#include <hip/hip_bf16.h>

typedef __attribute__((ext_vector_type(8))) short sh8;
typedef __attribute__((ext_vector_type(4))) float f4;
typedef unsigned short ushort_t;
typedef unsigned int uint_t;

// ---------- fast transcendentals (fp32) ----------
__device__ __forceinline__ float fast_rcp(float x) {
    return __builtin_amdgcn_rcpf(x);
}
__device__ __forceinline__ float sigmoidf_(float x) {
    return fast_rcp(1.f + __expf(-x));
}
__device__ __forceinline__ float tanhf_fast(float x) {
    float ax = fabsf(x);
    float e  = __expf(-2.f * ax);
    float t  = (1.f - e) * fast_rcp(1.f + e);
    return copysignf(t, x);
}

// ---------- bf16 split helpers (truncation; hi+lo ~ 2^-17 rel) ----------
__device__ __forceinline__ ushort_t bf16hi(float x) {
    return (ushort_t)(__float_as_uint(x) >> 16);
}
__device__ __forceinline__ float bf16tof(ushort_t u) {
    return __uint_as_float(((uint_t)u) << 16);
}

// ---------- conv1 (1->10, 5x5 VALID) + maxpool2 + tanh ----------
// x: [B,784] as 28x28, out COMPACT: [B,144,10]
__global__ __launch_bounds__(256) void conv1_pool_tanh(
    const float* __restrict__ x, const float* __restrict__ w,
    const float* __restrict__ bias, float* __restrict__ out)
{
    __shared__ float sw[250];
    __shared__ float sb[10];
    int t = threadIdx.x;
    if (t < 250) sw[t] = w[t];
    if (t < 10)  sb[t] = bias[t];
    __syncthreads();

    int gp  = blockIdx.x * 256 + t;
    int b   = gp / 144;
    int pix = gp % 144;
    int py = pix / 12, px = pix % 12;

    const float* img = x + (long)b * 784 + (2 * py) * 28 + 2 * px;
    float r[6][6];
#pragma unroll
    for (int ry = 0; ry < 6; ++ry)
#pragma unroll
        for (int rx = 0; rx < 6; ++rx)
            r[ry][rx] = img[ry * 28 + rx];

    float* ob = out + ((long)b * 144 + pix) * 10;
    for (int oc = 0; oc < 10; ++oc) {
        float a0 = 0.f, a1 = 0.f, a2 = 0.f, a3 = 0.f;
#pragma unroll
        for (int ky = 0; ky < 5; ++ky)
#pragma unroll
            for (int kx = 0; kx < 5; ++kx) {
                float wv = sw[oc * 25 + ky * 5 + kx];
                a0 += wv * r[ky][kx];
                a1 += wv * r[ky][kx + 1];
                a2 += wv * r[ky + 1][kx];
                a3 += wv * r[ky + 1][kx + 1];
            }
        float m = fmaxf(fmaxf(a0, a1), fmaxf(a2, a3)) + sb[oc];
        ob[oc] = tanhf_fast(m);
    }
}

// ---------- MFMA 2D-LSTM ----------
// x compact [B, H*W, CIN]; Wx [5H,CIN], Whl/Whu [5H,HID], bias [5H]
// out compact [B, H*W, HID].
template<int H, int W, int HID, int CIN, int KV, int NK, int NW, int VSTR, int GSTR>
__global__ __launch_bounds__(NW * 64) void mdlstm_mfma(
    const float* __restrict__ x, const float* __restrict__ Wx,
    const float* __restrict__ Whl, const float* __restrict__ Whu,
    const float* __restrict__ bias, float* __restrict__ out)
{
    constexpr int N    = H * W;
    constexpr int NT   = NW * 64;
    constexpr int NEPI = 16 * HID;
    constexpr int HL0  = CIN, HU0 = CIN + HID;
    constexpr int NXA  = 16 * CIN;
    constexpr int NSTG = 16 * W * CIN;
    static_assert(NW * 16 >= 5 * HID, "tiles cover gate rows");
    static_assert(KV >= CIN + 2 * HID, "K covers V");
    static_assert(NEPI <= NT && NXA <= NT, "thread budget");

    __shared__ ushort_t sV[16][VSTR];
    __shared__ float    sG[16][GSTR];
    __shared__ uint_t   sHrow[W][16][HID];
    __shared__ uint_t   sXrow[2][W][16][CIN];

    const int tid  = threadIdx.x;
    const int lane = tid & 63;
    const int wid  = tid >> 6;
    const int lr   = lane & 15;
    const int lg   = lane >> 4;
    const long bB  = (long)blockIdx.x * 16;

    sh8 Ah[NK], Al[NK];
    {
        const int r = wid * 16 + lr;
#pragma unroll
        for (int ks = 0; ks < NK; ++ks) {
#pragma unroll
            for (int e = 0; e < 8; ++e) {
                int k = ks * 32 + lg * 8 + e;
                float wv = 0.f;
                if (r < 5 * HID) {
                    if (k < CIN)            wv = Wx[r * CIN + k];
                    else if (k < HL0 + HID) wv = Whl[r * HID + (k - HL0)];
                    else if (k < HU0 + HID) wv = Whu[r * HID + (k - HU0)];
                }
                ushort_t hi = bf16hi(wv);
                Ah[ks][e] = (short)hi;
                Al[ks][e] = (short)bf16hi(wv - bf16tof(hi));
            }
        }
    }
    f4 biasF;
#pragma unroll
    for (int q = 0; q < 4; ++q) {
        int rr = wid * 16 + lg * 4 + q;
        biasF[q] = (rr < 5 * HID) ? bias[rr] : 0.f;
    }

    for (int idx = tid; idx < 16 * VSTR; idx += NT) (&sV[0][0])[idx] = 0;
    for (int idx = tid; idx < W * 16 * HID; idx += NT) (&sHrow[0][0][0])[idx] = 0;

    for (int idx = tid; idx < NSTG; idx += NT) {
        int batch = idx / (W * CIN);
        int rr    = idx % (W * CIN);
        float xv  = x[(bB + batch) * (N * CIN) + rr];
        ushort_t hi = bf16hi(xv);
        ushort_t lo = bf16hi(xv - bf16tof(hi));
        sXrow[0][rr / CIN][batch][rr % CIN] = ((uint_t)hi << 16) | lo;
    }
    __syncthreads();
    if (tid < NXA) {
        int batch = tid & 15, c = tid >> 4;
        uint_t xv = sXrow[0][0][batch][c];
        sV[batch][c]      = (ushort_t)(xv >> 16);
        sV[batch][KV + c] = (ushort_t)(xv & 0xffff);
    }
    __syncthreads();

    const int batch_e = tid & 15, j_e = tid >> 4;
    float c_row[W];
#pragma unroll
    for (int q = 0; q < W; ++q) c_row[q] = 0.f;

    for (int i = 0; i < H; ++i) {
        float c_left = 0.f;
#pragma unroll
        for (int jc = 0; jc < W; ++jc) {
            {
                sh8 Bh[NK];
#pragma unroll
                for (int ks = 0; ks < NK; ++ks)
                    Bh[ks] = *(const sh8*)&sV[lr][ks * 32 + lg * 8];
                f4 acc = __builtin_amdgcn_mfma_f32_16x16x32_bf16(
                             Ah[0], Bh[0], biasF, 0, 0, 0);
#pragma unroll
                for (int ks = 1; ks < NK; ++ks)
                    acc = __builtin_amdgcn_mfma_f32_16x16x32_bf16(
                              Ah[ks], Bh[ks], acc, 0, 0, 0);
#pragma unroll
                for (int ks = 0; ks < NK; ++ks) {
                    sh8 Bl = *(const sh8*)&sV[lr][KV + ks * 32 + lg * 8];
                    acc = __builtin_amdgcn_mfma_f32_16x16x32_bf16(
                              Ah[ks], Bl, acc, 0, 0, 0);
                }
#pragma unroll
                for (int ks = 0; ks < NK; ++ks)
                    acc = __builtin_amdgcn_mfma_f32_16x16x32_bf16(
                              Al[ks], Bh[ks], acc, 0, 0, 0);
                *(f4*)&sG[lr][wid * 16 + lg * 4] = acc;
            }
            if (jc == 0 && i + 1 < H) {
                const int nb = (i + 1) & 1;
                for (int idx = tid; idx < NSTG; idx += NT) {
                    int batch = idx / (W * CIN);
                    int rr    = idx % (W * CIN);
                    float xv  = x[(bB + batch) * (N * CIN) + (i + 1) * (W * CIN) + rr];
                    ushort_t hi = bf16hi(xv);
                    ushort_t lo = bf16hi(xv - bf16tof(hi));
                    sXrow[nb][rr / CIN][batch][rr % CIN] = ((uint_t)hi << 16) | lo;
                }
            }
            __syncthreads();
            if (tid < NEPI) {
                float g[5];
#pragma unroll
                for (int p = 0; p < 5; ++p) g[p] = sG[batch_e][j_e + HID * p];
                float ig  = sigmoidf_(g[0]), f1g = sigmoidf_(g[1]);
                float f2g = sigmoidf_(g[2]), og  = sigmoidf_(g[3]);
                float gg  = tanhf_fast(g[4]);
                float cc  = f1g * c_left + f2g * c_row[jc] + ig * gg;
                float hh  = og * tanhf_fast(cc);
                c_row[jc] = cc;
                c_left    = cc;
                ushort_t hhi = bf16hi(hh);
                ushort_t hlo = bf16hi(hh - bf16tof(hhi));
                if (jc < W - 1) {
                    sV[batch_e][HL0 + j_e]      = hhi;
                    sV[batch_e][KV + HL0 + j_e] = hlo;
                }
                sHrow[jc][batch_e][j_e] = ((uint_t)hhi << 16) | hlo;
                out[(bB + batch_e) * (long)(N * HID) + (i * W + jc) * HID + j_e] = hh;
            }
            if (i * W + jc < H * W - 1) {
                const int jc2 = (jc == W - 1) ? 0 : jc + 1;
                const int ib  = (jc == W - 1) ? ((i + 1) & 1) : (i & 1);
                if (tid >= NT - NEPI) {
                    int t2 = tid - (NT - NEPI);
                    int batch = t2 & 15, j2 = t2 >> 4;
                    uint_t hv = sHrow[jc2][batch][j2];
                    sV[batch][HU0 + j2]      = (ushort_t)(hv >> 16);
                    sV[batch][KV + HU0 + j2] = (ushort_t)(hv & 0xffff);
                }
                if (tid < NXA) {
                    int batch = tid & 15, c = tid >> 4;
                    uint_t xv = sXrow[ib][jc2][batch][c];
                    sV[batch][c]      = (ushort_t)(xv >> 16);
                    sV[batch][KV + c] = (ushort_t)(xv & 0xffff);
                }
                if (jc == W - 1 && tid < NEPI) {
                    sV[batch_e][HL0 + j_e]      = 0;
                    sV[batch_e][KV + HL0 + j_e] = 0;
                }
            }
            __syncthreads();
        }
    }
}

// ---------- prep: scatter conv2 weights into MFMA A-fragment layout ----------
// wt [30,20,5,5] -> wf shorts, sh8 index = (((tx*5+ty)*2+m)*2+h)*64 + lane,
// element e; lane=(kg*16+c), oc=m*16+c, ic=kg*8+e. h=0 hi, h=1 lo.
__global__ __launch_bounds__(256) void prep_conv2_frags(
    const float* __restrict__ wt, short* __restrict__ wf)
{
    int id = blockIdx.x * 256 + threadIdx.x;   // over 25*2*64*8 = 25600
    if (id >= 25600) return;
    int e    = id & 7;
    int lane = (id >> 3) & 63;
    int m    = (id >> 9) & 1;
    int tt   = id >> 10;            // tx*5+ty
    int tx = tt / 5, ty = tt % 5;
    int c = lane & 15, kg = lane >> 4;
    int oc = m * 16 + c, ic = kg * 8 + e;
    float wv = (oc < 30 && ic < 20) ? wt[((oc * 20 + ic) * 5 + ty) * 5 + tx] : 0.f;
    ushort_t hi = bf16hi(wv);
    ushort_t lo = bf16hi(wv - bf16tof(hi));
    wf[(((tt * 2 + m) * 2 + 0) * 64 + lane) * 8 + e] = (short)hi;
    wf[(((tt * 2 + m) * 2 + 1) * 64 + lane) * 8 + e] = (short)lo;
}

// ---------- conv2 stage helper: one float4 (4 channels of one pos) ----------
__device__ __forceinline__ void stage_f4(
    ushort_t (*Hi)[40], ushort_t (*Lo)[40], int f, float4 v)
{
    int pos = f / 5, q = f % 5;
    ushort_t h0 = bf16hi(v.x), h1 = bf16hi(v.y);
    ushort_t h2 = bf16hi(v.z), h3 = bf16hi(v.w);
    ushort_t l0 = bf16hi(v.x - bf16tof(h0));
    ushort_t l1 = bf16hi(v.y - bf16tof(h1));
    ushort_t l2 = bf16hi(v.z - bf16tof(h2));
    ushort_t l3 = bf16hi(v.w - bf16tof(h3));
    uint2 hp = { (uint_t)h0 | ((uint_t)h1 << 16), (uint_t)h2 | ((uint_t)h3 << 16) };
    uint2 lp = { (uint_t)l0 | ((uint_t)l1 << 16), (uint_t)l2 | ((uint_t)l3 << 16) };
    *(uint2*)&Hi[pos][q * 4] = hp;
    *(uint2*)&Lo[pos][q * 4] = lp;
}

// ---------- conv2 via tap-decomposed MFMA, 16 images/block ----------
// in COMPACT [B,144,20] fp32; wf frag weights; out COMPACT [B,16,30].
// Block = 16 images (grid 256 = 1/CU), 5 waves (wid = tx). Double-buffered
// image LDS: next image's loads issued before current image's MFMA loop.
__global__ __launch_bounds__(320, 2) void conv2_mfma(
    const float* __restrict__ in, const short* __restrict__ wf,
    const float* __restrict__ bias, float* __restrict__ out)
{
    constexpr int NIMG = 16;
    __shared__ ushort_t sHi[2][144][40];     // k 0..19 real, 20..39 zero
    __shared__ ushort_t sLo[2][144][40];
    __shared__ float    sPart[5][2][4][16][20]; // [wave][m][p][col][row+pad]
    __shared__ float    sB[30];

    const int tid  = threadIdx.x;
    const int lane = tid & 63;
    const int wid  = tid >> 6;          // = tx
    const int c    = lane & 15;
    const int kg   = lane >> 4;
    const long b0  = (long)blockIdx.x * NIMG;

    // ---- A-frags (coalesced, once per block) ----
    const sh8* wfv = (const sh8*)wf;
    sh8 Ah[5][2], Al[5][2];
#pragma unroll
    for (int ty = 0; ty < 5; ++ty)
#pragma unroll
        for (int m = 0; m < 2; ++m) {
            int base = (((wid * 5 + ty) * 2 + m) * 2) * 64 + lane;
            Ah[ty][m] = wfv[base];
            Al[ty][m] = wfv[base + 64];
        }

    // ---- zero channel pads (both buffers, once) ----
    for (int idx = tid; idx < 2 * 144 * 20; idx += 320) {
        int bb = idx / (144 * 20);
        int r  = idx % (144 * 20);
        int pos = r / 20, s = 20 + r % 20;
        sHi[bb][pos][s] = 0;
        sLo[bb][pos][s] = 0;
    }
    if (tid < 30) sB[tid] = bias[tid];

    // ---- stage image 0 into buffer 0 (3 independent float4 loads) ----
    {
        const float* p = in + b0 * 2880;
        float4 v0 = *(const float4*)(p + 4 * tid);
        float4 v1 = *(const float4*)(p + 4 * (tid + 320));
        float4 v2 = {0.f, 0.f, 0.f, 0.f};
        if (tid < 80) v2 = *(const float4*)(p + 4 * (tid + 640));
        stage_f4(sHi[0], sLo[0], tid, v0);
        stage_f4(sHi[0], sLo[0], tid + 320, v1);
        if (tid < 80) stage_f4(sHi[0], sLo[0], tid + 640, v2);
    }
    __syncthreads();

    const int y0 = c >> 3, x = c & 7;   // conv pixel within tile: n = p*16+c
    for (int img = 0; img < NIMG; ++img) {
        const int cb = img & 1;
        // issue next image's loads (latency hides under MFMA loop)
        float4 v0, v1, v2;
        const bool have = (img + 1 < NIMG);
        if (have) {
            const float* p = in + (b0 + img + 1) * 2880;
            v0 = *(const float4*)(p + 4 * tid);
            v1 = *(const float4*)(p + 4 * (tid + 320));
            if (tid < 80) v2 = *(const float4*)(p + 4 * (tid + 640));
        }
        // main: 4 pixel tiles; 6 independent MFMA chains each
#pragma unroll
        for (int p4 = 0; p4 < 4; ++p4) {
            const int pos = (2 * p4 + y0) * 12 + x + wid;
            const ushort_t* bh = &sHi[cb][pos][kg * 8];
            const ushort_t* bl = &sLo[cb][pos][kg * 8];
            f4 hh0 = {0.f,0.f,0.f,0.f}, hl0 = {0.f,0.f,0.f,0.f}, lh0 = {0.f,0.f,0.f,0.f};
            f4 hh1 = {0.f,0.f,0.f,0.f}, hl1 = {0.f,0.f,0.f,0.f}, lh1 = {0.f,0.f,0.f,0.f};
#pragma unroll
            for (int ks = 0; ks < 5; ++ks) {
                sh8 Bh = *(const sh8*)(bh + ks * 12 * 40);
                sh8 Bl = *(const sh8*)(bl + ks * 12 * 40);
                hh0 = __builtin_amdgcn_mfma_f32_16x16x32_bf16(Ah[ks][0], Bh, hh0, 0, 0, 0);
                hl0 = __builtin_amdgcn_mfma_f32_16x16x32_bf16(Ah[ks][0], Bl, hl0, 0, 0, 0);
                lh0 = __builtin_amdgcn_mfma_f32_16x16x32_bf16(Al[ks][0], Bh, lh0, 0, 0, 0);
                hh1 = __builtin_amdgcn_mfma_f32_16x16x32_bf16(Ah[ks][1], Bh, hh1, 0, 0, 0);
                hl1 = __builtin_amdgcn_mfma_f32_16x16x32_bf16(Ah[ks][1], Bl, hl1, 0, 0, 0);
                lh1 = __builtin_amdgcn_mfma_f32_16x16x32_bf16(Al[ks][1], Bh, lh1, 0, 0, 0);
            }
            f4 c0 = hh0 + hl0 + lh0;
            f4 c1 = hh1 + hl1 + lh1;
            *(f4*)&sPart[wid][0][p4][c][kg * 4] = c0;
            *(f4*)&sPart[wid][1][p4][c][kg * 4] = c1;
        }
        // write next image into the other buffer
        if (have) {
            stage_f4(sHi[cb ^ 1], sLo[cb ^ 1], tid, v0);
            stage_f4(sHi[cb ^ 1], sLo[cb ^ 1], tid + 320, v1);
            if (tid < 80) stage_f4(sHi[cb ^ 1], sLo[cb ^ 1], tid + 640, v2);
        }
        __syncthreads();
        // fused cross-wave sum + bias + 2x2 maxpool + tanh
        for (int idx = tid; idx < 480; idx += 320) {
            int pix = idx / 30, oc = idx % 30;
            int m = oc >> 4, r = oc & 15;
            int py = pix >> 2, px = pix & 3;
            float vmax = -1e30f;
#pragma unroll
            for (int dy = 0; dy < 2; ++dy)
#pragma unroll
                for (int dx = 0; dx < 2; ++dx) {
                    int n = (2 * py + dy) * 8 + 2 * px + dx;
                    float s = 0.f;
#pragma unroll
                    for (int w = 0; w < 5; ++w)
                        s += sPart[w][m][n >> 4][n & 15][r];
                    vmax = fmaxf(vmax, s);
                }
            out[(b0 + img) * 480 + idx] = tanhf_fast(vmax + sB[oc]);
        }
        __syncthreads();   // sPart / buffers safe to overwrite
    }
}

// ---------- fc1 (640->100) + tanh ----------
// in COMPACT [B,16,40] (k' = pix*40+hid); w [100,640] with k = hid*16+pix.
__global__ __launch_bounds__(256) void fc1_tanh(
    const float* __restrict__ in, const float* __restrict__ w,
    const float* __restrict__ bias, float* __restrict__ out)
{
    int t = threadIdx.x;
    int bblk = blockIdx.x & 15;
    int o    = blockIdx.x >> 4;
    long b = (long)bblk * 256 + t;
    const float* wr = w + o * 640;
    const float* xr = in + b * 640;
    float acc = 0.f;
#pragma unroll 4
    for (int pix = 0; pix < 16; ++pix) {
        const float* xp = xr + pix * 40;
#pragma unroll
        for (int hid = 0; hid < 40; hid += 4) {
            float4 xv = *(const float4*)(xp + hid);
            acc += wr[(hid + 0) * 16 + pix] * xv.x
                 + wr[(hid + 1) * 16 + pix] * xv.y
                 + wr[(hid + 2) * 16 + pix] * xv.z
                 + wr[(hid + 3) * 16 + pix] * xv.w;
        }
    }
    out[b * 100 + o] = tanhf_fast(acc + bias[o]);
}

// ---------- fc2 (100->10) + softmax ----------
__global__ __launch_bounds__(64) void fc2_softmax(
    const float* __restrict__ in, const float* __restrict__ w,
    const float* __restrict__ bias, float* __restrict__ out)
{
    long b = (long)blockIdx.x * 64 + threadIdx.x;
    const float* xr = in + b * 100;
    float logit[10];
#pragma unroll
    for (int o = 0; o < 10; ++o) logit[o] = bias[o];
    for (int k = 0; k < 100; ++k) {
        float xv = xr[k];
#pragma unroll
        for (int o = 0; o < 10; ++o) logit[o] += xv * w[o * 100 + k];
    }
    float m = logit[0];
#pragma unroll
    for (int o = 1; o < 10; ++o) m = fmaxf(m, logit[o]);
    float s = 0.f;
#pragma unroll
    for (int o = 0; o < 10; ++o) { logit[o] = __expf(logit[o] - m); s += logit[o]; }
    float inv = fast_rcp(s);
#pragma unroll
    for (int o = 0; o < 10; ++o) out[b * 10 + o] = logit[o] * inv;
}

extern "C" void kernel_launch(void* const* d_in, const int* in_sizes, int n_in,
                              void* d_out, int out_size, void* d_ws, size_t ws_size,
                              hipStream_t stream)
{
    const float* x    = (const float*)d_in[0];
    const float* c1w  = (const float*)d_in[1];
    const float* c1b  = (const float*)d_in[2];
    const float* m1Wx = (const float*)d_in[3];
    const float* m1Wl = (const float*)d_in[4];
    const float* m1Wu = (const float*)d_in[5];
    const float* m1b  = (const float*)d_in[6];
    const float* c2w  = (const float*)d_in[7];
    const float* c2b  = (const float*)d_in[8];
    const float* m2Wx = (const float*)d_in[9];
    const float* m2Wl = (const float*)d_in[10];
    const float* m2Wu = (const float*)d_in[11];
    const float* m2b  = (const float*)d_in[12];
    const float* f1w  = (const float*)d_in[13];
    const float* f1b  = (const float*)d_in[14];
    const float* f2w  = (const float*)d_in[15];
    const float* f2b  = (const float*)d_in[16];
    float* outp = (float*)d_out;

    char* ws = (char*)d_ws;
    float* a1 = (float*)ws;                 // [B,144,10] 23.6 MB
    float* h1 = (float*)(ws + 23592960);    // [B,144,20] 47.2 MB
    float* a2 = a1;                         // [B,16,30] 7.86 MB (reuse a1)
    short* wfrag = (short*)(ws + 8388608);  // 102 KB, inside dead a1 region (>a2)
    float* h2 = h1;                         // [B,16,40] reuse
    float* f1 = a1;                         // [B,100]   reuse

    conv1_pool_tanh<<<2304, 256, 0, stream>>>(x, c1w, c1b, a1);
    // m1: V=[x10|hl20|hu20] pad KV=64, NK=2, 7 M-tiles (112 rows)
    mdlstm_mfma<12, 12, 20, 10, 64, 2, 7, 136, 116><<<256, 448, 0, stream>>>(
        a1, m1Wx, m1Wl, m1Wu, m1b, h1);
    prep_conv2_frags<<<100, 256, 0, stream>>>(c2w, wfrag);   // a1 dead now
    conv2_mfma<<<256, 320, 0, stream>>>(h1, wfrag, c2b, a2);
    // m2: V=[x30|hl40|hu40] pad KV=128, NK=4, 13 M-tiles (208 rows)
    mdlstm_mfma<4, 4, 40, 30, 128, 4, 13, 264, 212><<<256, 832, 0, stream>>>(
        a2, m2Wx, m2Wl, m2Wu, m2b, h2);
    fc1_tanh<<<1600, 256, 0, stream>>>(h2, f1w, f1b, f1);
    fc2_softmax<<<64, 64, 0, stream>>>(f1, f2w, f2b, outp);
}

// Round 8
// 227.838 us; speedup vs baseline: 3.1154x; 1.5546x over previous
//
#include <hip/hip_runtime.h>
#include <hip/hip_bf16.h>

typedef __attribute__((ext_vector_type(8))) short sh8;
typedef __attribute__((ext_vector_type(4))) float f4;
typedef unsigned short ushort_t;
typedef unsigned int uint_t;

// ---------- fast transcendentals (fp32) ----------
__device__ __forceinline__ float fast_rcp(float x) {
    return __builtin_amdgcn_rcpf(x);
}
__device__ __forceinline__ float sigmoidf_(float x) {
    return fast_rcp(1.f + __expf(-x));
}
__device__ __forceinline__ float tanhf_fast(float x) {
    float ax = fabsf(x);
    float e  = __expf(-2.f * ax);
    float t  = (1.f - e) * fast_rcp(1.f + e);
    return copysignf(t, x);
}

// ---------- bf16 split helpers (truncation; hi+lo ~ 2^-17 rel) ----------
__device__ __forceinline__ ushort_t bf16hi(float x) {
    return (ushort_t)(__float_as_uint(x) >> 16);
}
__device__ __forceinline__ float bf16tof(ushort_t u) {
    return __uint_as_float(((uint_t)u) << 16);
}

// ---------- conv1 (1->10, 5x5 VALID) + maxpool2 + tanh ----------
// x: [B,784] as 28x28, out COMPACT: [B,144,10]
__global__ __launch_bounds__(256) void conv1_pool_tanh(
    const float* __restrict__ x, const float* __restrict__ w,
    const float* __restrict__ bias, float* __restrict__ out)
{
    __shared__ float sw[250];
    __shared__ float sb[10];
    int t = threadIdx.x;
    if (t < 250) sw[t] = w[t];
    if (t < 10)  sb[t] = bias[t];
    __syncthreads();

    int gp  = blockIdx.x * 256 + t;
    int b   = gp / 144;
    int pix = gp % 144;
    int py = pix / 12, px = pix % 12;

    const float* img = x + (long)b * 784 + (2 * py) * 28 + 2 * px;
    float r[6][6];
#pragma unroll
    for (int ry = 0; ry < 6; ++ry)
#pragma unroll
        for (int rx = 0; rx < 6; ++rx)
            r[ry][rx] = img[ry * 28 + rx];

    float* ob = out + ((long)b * 144 + pix) * 10;
    for (int oc = 0; oc < 10; ++oc) {
        float a0 = 0.f, a1 = 0.f, a2 = 0.f, a3 = 0.f;
#pragma unroll
        for (int ky = 0; ky < 5; ++ky)
#pragma unroll
            for (int kx = 0; kx < 5; ++kx) {
                float wv = sw[oc * 25 + ky * 5 + kx];
                a0 += wv * r[ky][kx];
                a1 += wv * r[ky][kx + 1];
                a2 += wv * r[ky + 1][kx];
                a3 += wv * r[ky + 1][kx + 1];
            }
        float m = fmaxf(fmaxf(a0, a1), fmaxf(a2, a3)) + sb[oc];
        ob[oc] = tanhf_fast(m);
    }
}

// ---------- MFMA 2D-LSTM ----------
// x compact [B, H*W, CIN]; Wx [5H,CIN], Whl/Whu [5H,HID], bias [5H]
// out compact [B, H*W, HID].
template<int H, int W, int HID, int CIN, int KV, int NK, int NW, int VSTR, int GSTR>
__global__ __launch_bounds__(NW * 64) void mdlstm_mfma(
    const float* __restrict__ x, const float* __restrict__ Wx,
    const float* __restrict__ Whl, const float* __restrict__ Whu,
    const float* __restrict__ bias, float* __restrict__ out)
{
    constexpr int N    = H * W;
    constexpr int NT   = NW * 64;
    constexpr int NEPI = 16 * HID;
    constexpr int HL0  = CIN, HU0 = CIN + HID;
    constexpr int NXA  = 16 * CIN;
    constexpr int NSTG = 16 * W * CIN;
    static_assert(NW * 16 >= 5 * HID, "tiles cover gate rows");
    static_assert(KV >= CIN + 2 * HID, "K covers V");
    static_assert(NEPI <= NT && NXA <= NT, "thread budget");

    __shared__ ushort_t sV[16][VSTR];
    __shared__ float    sG[16][GSTR];
    __shared__ uint_t   sHrow[W][16][HID];
    __shared__ uint_t   sXrow[2][W][16][CIN];

    const int tid  = threadIdx.x;
    const int lane = tid & 63;
    const int wid  = tid >> 6;
    const int lr   = lane & 15;
    const int lg   = lane >> 4;
    const long bB  = (long)blockIdx.x * 16;

    sh8 Ah[NK], Al[NK];
    {
        const int r = wid * 16 + lr;
#pragma unroll
        for (int ks = 0; ks < NK; ++ks) {
#pragma unroll
            for (int e = 0; e < 8; ++e) {
                int k = ks * 32 + lg * 8 + e;
                float wv = 0.f;
                if (r < 5 * HID) {
                    if (k < CIN)            wv = Wx[r * CIN + k];
                    else if (k < HL0 + HID) wv = Whl[r * HID + (k - HL0)];
                    else if (k < HU0 + HID) wv = Whu[r * HID + (k - HU0)];
                }
                ushort_t hi = bf16hi(wv);
                Ah[ks][e] = (short)hi;
                Al[ks][e] = (short)bf16hi(wv - bf16tof(hi));
            }
        }
    }
    f4 biasF;
#pragma unroll
    for (int q = 0; q < 4; ++q) {
        int rr = wid * 16 + lg * 4 + q;
        biasF[q] = (rr < 5 * HID) ? bias[rr] : 0.f;
    }

    for (int idx = tid; idx < 16 * VSTR; idx += NT) (&sV[0][0])[idx] = 0;
    for (int idx = tid; idx < W * 16 * HID; idx += NT) (&sHrow[0][0][0])[idx] = 0;

    for (int idx = tid; idx < NSTG; idx += NT) {
        int batch = idx / (W * CIN);
        int rr    = idx % (W * CIN);
        float xv  = x[(bB + batch) * (N * CIN) + rr];
        ushort_t hi = bf16hi(xv);
        ushort_t lo = bf16hi(xv - bf16tof(hi));
        sXrow[0][rr / CIN][batch][rr % CIN] = ((uint_t)hi << 16) | lo;
    }
    __syncthreads();
    if (tid < NXA) {
        int batch = tid & 15, c = tid >> 4;
        uint_t xv = sXrow[0][0][batch][c];
        sV[batch][c]      = (ushort_t)(xv >> 16);
        sV[batch][KV + c] = (ushort_t)(xv & 0xffff);
    }
    __syncthreads();

    const int batch_e = tid & 15, j_e = tid >> 4;
    float c_row[W];
#pragma unroll
    for (int q = 0; q < W; ++q) c_row[q] = 0.f;

    for (int i = 0; i < H; ++i) {
        float c_left = 0.f;
#pragma unroll
        for (int jc = 0; jc < W; ++jc) {
            {
                sh8 Bh[NK];
#pragma unroll
                for (int ks = 0; ks < NK; ++ks)
                    Bh[ks] = *(const sh8*)&sV[lr][ks * 32 + lg * 8];
                f4 acc = __builtin_amdgcn_mfma_f32_16x16x32_bf16(
                             Ah[0], Bh[0], biasF, 0, 0, 0);
#pragma unroll
                for (int ks = 1; ks < NK; ++ks)
                    acc = __builtin_amdgcn_mfma_f32_16x16x32_bf16(
                              Ah[ks], Bh[ks], acc, 0, 0, 0);
#pragma unroll
                for (int ks = 0; ks < NK; ++ks) {
                    sh8 Bl = *(const sh8*)&sV[lr][KV + ks * 32 + lg * 8];
                    acc = __builtin_amdgcn_mfma_f32_16x16x32_bf16(
                              Ah[ks], Bl, acc, 0, 0, 0);
                }
#pragma unroll
                for (int ks = 0; ks < NK; ++ks)
                    acc = __builtin_amdgcn_mfma_f32_16x16x32_bf16(
                              Al[ks], Bh[ks], acc, 0, 0, 0);
                *(f4*)&sG[lr][wid * 16 + lg * 4] = acc;
            }
            if (jc == 0 && i + 1 < H) {
                const int nb = (i + 1) & 1;
                for (int idx = tid; idx < NSTG; idx += NT) {
                    int batch = idx / (W * CIN);
                    int rr    = idx % (W * CIN);
                    float xv  = x[(bB + batch) * (N * CIN) + (i + 1) * (W * CIN) + rr];
                    ushort_t hi = bf16hi(xv);
                    ushort_t lo = bf16hi(xv - bf16tof(hi));
                    sXrow[nb][rr / CIN][batch][rr % CIN] = ((uint_t)hi << 16) | lo;
                }
            }
            __syncthreads();
            if (tid < NEPI) {
                float g[5];
#pragma unroll
                for (int p = 0; p < 5; ++p) g[p] = sG[batch_e][j_e + HID * p];
                float ig  = sigmoidf_(g[0]), f1g = sigmoidf_(g[1]);
                float f2g = sigmoidf_(g[2]), og  = sigmoidf_(g[3]);
                float gg  = tanhf_fast(g[4]);
                float cc  = f1g * c_left + f2g * c_row[jc] + ig * gg;
                float hh  = og * tanhf_fast(cc);
                c_row[jc] = cc;
                c_left    = cc;
                ushort_t hhi = bf16hi(hh);
                ushort_t hlo = bf16hi(hh - bf16tof(hhi));
                if (jc < W - 1) {
                    sV[batch_e][HL0 + j_e]      = hhi;
                    sV[batch_e][KV + HL0 + j_e] = hlo;
                }
                sHrow[jc][batch_e][j_e] = ((uint_t)hhi << 16) | hlo;
                out[(bB + batch_e) * (long)(N * HID) + (i * W + jc) * HID + j_e] = hh;
            }
            if (i * W + jc < H * W - 1) {
                const int jc2 = (jc == W - 1) ? 0 : jc + 1;
                const int ib  = (jc == W - 1) ? ((i + 1) & 1) : (i & 1);
                if (tid >= NT - NEPI) {
                    int t2 = tid - (NT - NEPI);
                    int batch = t2 & 15, j2 = t2 >> 4;
                    uint_t hv = sHrow[jc2][batch][j2];
                    sV[batch][HU0 + j2]      = (ushort_t)(hv >> 16);
                    sV[batch][KV + HU0 + j2] = (ushort_t)(hv & 0xffff);
                }
                if (tid < NXA) {
                    int batch = tid & 15, c = tid >> 4;
                    uint_t xv = sXrow[ib][jc2][batch][c];
                    sV[batch][c]      = (ushort_t)(xv >> 16);
                    sV[batch][KV + c] = (ushort_t)(xv & 0xffff);
                }
                if (jc == W - 1 && tid < NEPI) {
                    sV[batch_e][HL0 + j_e]      = 0;
                    sV[batch_e][KV + HL0 + j_e] = 0;
                }
            }
            __syncthreads();
        }
    }
}

// ---------- prep: scatter conv2 weights into MFMA A-fragment layout ----------
__global__ __launch_bounds__(256) void prep_conv2_frags(
    const float* __restrict__ wt, short* __restrict__ wf)
{
    int id = blockIdx.x * 256 + threadIdx.x;   // over 25*2*64*8 = 25600
    if (id >= 25600) return;
    int e    = id & 7;
    int lane = (id >> 3) & 63;
    int m    = (id >> 9) & 1;
    int tt   = id >> 10;            // tx*5+ty
    int tx = tt / 5, ty = tt % 5;
    int c = lane & 15, kg = lane >> 4;
    int oc = m * 16 + c, ic = kg * 8 + e;
    float wv = (oc < 30 && ic < 20) ? wt[((oc * 20 + ic) * 5 + ty) * 5 + tx] : 0.f;
    ushort_t hi = bf16hi(wv);
    ushort_t lo = bf16hi(wv - bf16tof(hi));
    wf[(((tt * 2 + m) * 2 + 0) * 64 + lane) * 8 + e] = (short)hi;
    wf[(((tt * 2 + m) * 2 + 1) * 64 + lane) * 8 + e] = (short)lo;
}

// ---------- prep: scatter fc1 weights into MFMA A-fragment layout ----------
// w1 [100,640] (ref k = hid*16+pix); our k' = pix*40+hid (compact [B,16,40]).
// wf1 sh8 index = ((m*20+ks)*2+h)*64+lane; o=m*16+(lane&15), k'=ks*32+(lane>>4)*8+e
__global__ __launch_bounds__(256) void prep_fc1_frags(
    const float* __restrict__ w1, short* __restrict__ wf1)
{
    int id = blockIdx.x * 256 + threadIdx.x;   // over 7*20*2*64*8 = 143360
    if (id >= 143360) return;
    int e    = id & 7;
    int r    = id >> 3;
    int lane = r & 63;  r >>= 6;
    int h    = r & 1;   r >>= 1;
    int ks   = r % 20;
    int m    = r / 20;
    int o  = m * 16 + (lane & 15);
    int kp = ks * 32 + (lane >> 4) * 8 + e;
    int pix = kp / 40, hid = kp % 40;
    float wv = (o < 100) ? w1[o * 640 + hid * 16 + pix] : 0.f;
    ushort_t hi = bf16hi(wv);
    ushort_t v  = h ? (ushort_t)bf16hi(wv - bf16tof(hi)) : hi;
    wf1[id] = (short)v;
}

// ---------- conv2 stage helper: one float4 (4 channels of one pos) ----------
__device__ __forceinline__ void stage_f4(
    ushort_t (*Hi)[40], ushort_t (*Lo)[40], int f, float4 v)
{
    int pos = f / 5, q = f % 5;
    ushort_t h0 = bf16hi(v.x), h1 = bf16hi(v.y);
    ushort_t h2 = bf16hi(v.z), h3 = bf16hi(v.w);
    ushort_t l0 = bf16hi(v.x - bf16tof(h0));
    ushort_t l1 = bf16hi(v.y - bf16tof(h1));
    ushort_t l2 = bf16hi(v.z - bf16tof(h2));
    ushort_t l3 = bf16hi(v.w - bf16tof(h3));
    uint2 hp = { (uint_t)h0 | ((uint_t)h1 << 16), (uint_t)h2 | ((uint_t)h3 << 16) };
    uint2 lp = { (uint_t)l0 | ((uint_t)l1 << 16), (uint_t)l2 | ((uint_t)l3 << 16) };
    *(uint2*)&Hi[pos][q * 4] = hp;
    *(uint2*)&Lo[pos][q * 4] = lp;
}

// ---------- conv2 via tap-decomposed MFMA, 16 images/block ----------
__global__ __launch_bounds__(320, 2) void conv2_mfma(
    const float* __restrict__ in, const short* __restrict__ wf,
    const float* __restrict__ bias, float* __restrict__ out)
{
    constexpr int NIMG = 16;
    __shared__ ushort_t sHi[2][144][40];
    __shared__ ushort_t sLo[2][144][40];
    __shared__ float    sPart[5][2][4][16][20];
    __shared__ float    sB[30];

    const int tid  = threadIdx.x;
    const int lane = tid & 63;
    const int wid  = tid >> 6;          // = tx
    const int c    = lane & 15;
    const int kg   = lane >> 4;
    const long b0  = (long)blockIdx.x * NIMG;

    const sh8* wfv = (const sh8*)wf;
    sh8 Ah[5][2], Al[5][2];
#pragma unroll
    for (int ty = 0; ty < 5; ++ty)
#pragma unroll
        for (int m = 0; m < 2; ++m) {
            int base = (((wid * 5 + ty) * 2 + m) * 2) * 64 + lane;
            Ah[ty][m] = wfv[base];
            Al[ty][m] = wfv[base + 64];
        }

    for (int idx = tid; idx < 2 * 144 * 20; idx += 320) {
        int bb = idx / (144 * 20);
        int r  = idx % (144 * 20);
        int pos = r / 20, s = 20 + r % 20;
        sHi[bb][pos][s] = 0;
        sLo[bb][pos][s] = 0;
    }
    if (tid < 30) sB[tid] = bias[tid];

    {
        const float* p = in + b0 * 2880;
        float4 v0 = *(const float4*)(p + 4 * tid);
        float4 v1 = *(const float4*)(p + 4 * (tid + 320));
        float4 v2 = {0.f, 0.f, 0.f, 0.f};
        if (tid < 80) v2 = *(const float4*)(p + 4 * (tid + 640));
        stage_f4(sHi[0], sLo[0], tid, v0);
        stage_f4(sHi[0], sLo[0], tid + 320, v1);
        if (tid < 80) stage_f4(sHi[0], sLo[0], tid + 640, v2);
    }
    __syncthreads();

    const int y0 = c >> 3, x = c & 7;
    for (int img = 0; img < NIMG; ++img) {
        const int cb = img & 1;
        float4 v0, v1, v2;
        const bool have = (img + 1 < NIMG);
        if (have) {
            const float* p = in + (b0 + img + 1) * 2880;
            v0 = *(const float4*)(p + 4 * tid);
            v1 = *(const float4*)(p + 4 * (tid + 320));
            if (tid < 80) v2 = *(const float4*)(p + 4 * (tid + 640));
        }
#pragma unroll
        for (int p4 = 0; p4 < 4; ++p4) {
            const int pos = (2 * p4 + y0) * 12 + x + wid;
            const ushort_t* bh = &sHi[cb][pos][kg * 8];
            const ushort_t* bl = &sLo[cb][pos][kg * 8];
            f4 hh0 = {0.f,0.f,0.f,0.f}, hl0 = {0.f,0.f,0.f,0.f}, lh0 = {0.f,0.f,0.f,0.f};
            f4 hh1 = {0.f,0.f,0.f,0.f}, hl1 = {0.f,0.f,0.f,0.f}, lh1 = {0.f,0.f,0.f,0.f};
#pragma unroll
            for (int ks = 0; ks < 5; ++ks) {
                sh8 Bh = *(const sh8*)(bh + ks * 12 * 40);
                sh8 Bl = *(const sh8*)(bl + ks * 12 * 40);
                hh0 = __builtin_amdgcn_mfma_f32_16x16x32_bf16(Ah[ks][0], Bh, hh0, 0, 0, 0);
                hl0 = __builtin_amdgcn_mfma_f32_16x16x32_bf16(Ah[ks][0], Bl, hl0, 0, 0, 0);
                lh0 = __builtin_amdgcn_mfma_f32_16x16x32_bf16(Al[ks][0], Bh, lh0, 0, 0, 0);
                hh1 = __builtin_amdgcn_mfma_f32_16x16x32_bf16(Ah[ks][1], Bh, hh1, 0, 0, 0);
                hl1 = __builtin_amdgcn_mfma_f32_16x16x32_bf16(Ah[ks][1], Bl, hl1, 0, 0, 0);
                lh1 = __builtin_amdgcn_mfma_f32_16x16x32_bf16(Al[ks][1], Bh, lh1, 0, 0, 0);
            }
            f4 c0 = hh0 + hl0 + lh0;
            f4 c1 = hh1 + hl1 + lh1;
            *(f4*)&sPart[wid][0][p4][c][kg * 4] = c0;
            *(f4*)&sPart[wid][1][p4][c][kg * 4] = c1;
        }
        if (have) {
            stage_f4(sHi[cb ^ 1], sLo[cb ^ 1], tid, v0);
            stage_f4(sHi[cb ^ 1], sLo[cb ^ 1], tid + 320, v1);
            if (tid < 80) stage_f4(sHi[cb ^ 1], sLo[cb ^ 1], tid + 640, v2);
        }
        __syncthreads();
        for (int idx = tid; idx < 480; idx += 320) {
            int pix = idx / 30, oc = idx % 30;
            int m = oc >> 4, r = oc & 15;
            int py = pix >> 2, px = pix & 3;
            float vmax = -1e30f;
#pragma unroll
            for (int dy = 0; dy < 2; ++dy)
#pragma unroll
                for (int dx = 0; dx < 2; ++dx) {
                    int n = (2 * py + dy) * 8 + 2 * px + dx;
                    float s = 0.f;
#pragma unroll
                    for (int w = 0; w < 5; ++w)
                        s += sPart[w][m][n >> 4][n & 15][r];
                    vmax = fmaxf(vmax, s);
                }
            out[(b0 + img) * 480 + idx] = tanhf_fast(vmax + sB[oc]);
        }
        __syncthreads();
    }
}

// ---------- fused fc1(640->100)+tanh + fc2(100->10) + softmax ----------
// in COMPACT [B,16,40] fp32 = [B][640] (k'); wf1 frag weights; out [B,10].
// Block = 16 batches, 7 waves (M-tiles over 112 rows >= 100 outputs).
__global__ __launch_bounds__(448) void fc_fused(
    const float* __restrict__ in, const short* __restrict__ wf1,
    const float* __restrict__ b1, const float* __restrict__ w2,
    const float* __restrict__ b2, float* __restrict__ out)
{
    constexpr int XS = 648;      // padded row stride (ushorts)
    __shared__ ushort_t sXh[16][XS];
    __shared__ ushort_t sXl[16][XS];
    __shared__ float    sG[16][116];
    __shared__ float    sF[16][101];
    __shared__ float    sW2[1000];
    __shared__ float    sB2[10];
    __shared__ float    sL[16][12];

    const int tid  = threadIdx.x;
    const int lane = tid & 63;
    const int wid  = tid >> 6;
    const int lr   = lane & 15;
    const int lg   = lane >> 4;
    const long b0  = (long)blockIdx.x * 16;

    // ---- stage x tile (coalesced float4), bf16 hi/lo split ----
    for (int idx = tid; idx < 2560; idx += 448) {
        int flat = idx * 4;
        int row = flat / 640, col = flat % 640;
        float4 v = *(const float4*)(in + (b0 + row) * 640 + col);
        ushort_t h0 = bf16hi(v.x), h1 = bf16hi(v.y);
        ushort_t h2 = bf16hi(v.z), h3 = bf16hi(v.w);
        uint2 hp = { (uint_t)h0 | ((uint_t)h1 << 16), (uint_t)h2 | ((uint_t)h3 << 16) };
        ushort_t l0 = bf16hi(v.x - bf16tof(h0));
        ushort_t l1 = bf16hi(v.y - bf16tof(h1));
        ushort_t l2 = bf16hi(v.z - bf16tof(h2));
        ushort_t l3 = bf16hi(v.w - bf16tof(h3));
        uint2 lp = { (uint_t)l0 | ((uint_t)l1 << 16), (uint_t)l2 | ((uint_t)l3 << 16) };
        *(uint2*)&sXh[row][col] = hp;
        *(uint2*)&sXl[row][col] = lp;
    }
    for (int idx = tid; idx < 1000; idx += 448) sW2[idx] = w2[idx];
    if (tid < 10) sB2[tid] = b2[tid];

    f4 biasF;
#pragma unroll
    for (int q = 0; q < 4; ++q) {
        int rr = wid * 16 + lg * 4 + q;
        biasF[q] = (rr < 100) ? b1[rr] : 0.f;
    }
    __syncthreads();

    // ---- GEMM: 20 K-steps, 3 independent split-term chains ----
    {
        const sh8* wfv = (const sh8*)wf1;
        f4 hh = biasF, hl = {0.f,0.f,0.f,0.f}, lh = {0.f,0.f,0.f,0.f};
#pragma unroll
        for (int ks = 0; ks < 20; ++ks) {
            int base = ((wid * 20 + ks) * 2) * 64 + lane;
            sh8 Ah = wfv[base];
            sh8 Al = wfv[base + 64];
            sh8 Bh = *(const sh8*)&sXh[lr][ks * 32 + lg * 8];
            sh8 Bl = *(const sh8*)&sXl[lr][ks * 32 + lg * 8];
            hh = __builtin_amdgcn_mfma_f32_16x16x32_bf16(Ah, Bh, hh, 0, 0, 0);
            hl = __builtin_amdgcn_mfma_f32_16x16x32_bf16(Ah, Bl, hl, 0, 0, 0);
            lh = __builtin_amdgcn_mfma_f32_16x16x32_bf16(Al, Bh, lh, 0, 0, 0);
        }
        f4 acc = hh + hl + lh;
        *(f4*)&sG[lr][wid * 16 + lg * 4] = acc;
    }
    __syncthreads();

    // ---- fc1 tanh ----
    for (int idx = tid; idx < 1600; idx += 448) {
        int bb = idx / 100, o = idx % 100;
        sF[bb][o] = tanhf_fast(sG[bb][o]);
    }
    __syncthreads();

    // ---- fc2: 160 threads (o2, batch) ----
    if (tid < 160) {
        int o2 = tid >> 4, bb = tid & 15;
        const float* wr = &sW2[o2 * 100];
        float acc = sB2[o2];
        for (int k = 0; k < 100; ++k) acc += sF[bb][k] * wr[k];
        sL[bb][o2] = acc;
    }
    __syncthreads();

    // ---- softmax: 16 threads, one batch each ----
    if (tid < 16) {
        float lg10[10];
#pragma unroll
        for (int o = 0; o < 10; ++o) lg10[o] = sL[tid][o];
        float m = lg10[0];
#pragma unroll
        for (int o = 1; o < 10; ++o) m = fmaxf(m, lg10[o]);
        float s = 0.f;
#pragma unroll
        for (int o = 0; o < 10; ++o) { lg10[o] = __expf(lg10[o] - m); s += lg10[o]; }
        float inv = fast_rcp(s);
        float* ob = out + (b0 + tid) * 10;
#pragma unroll
        for (int o = 0; o < 10; ++o) ob[o] = lg10[o] * inv;
    }
}

extern "C" void kernel_launch(void* const* d_in, const int* in_sizes, int n_in,
                              void* d_out, int out_size, void* d_ws, size_t ws_size,
                              hipStream_t stream)
{
    const float* x    = (const float*)d_in[0];
    const float* c1w  = (const float*)d_in[1];
    const float* c1b  = (const float*)d_in[2];
    const float* m1Wx = (const float*)d_in[3];
    const float* m1Wl = (const float*)d_in[4];
    const float* m1Wu = (const float*)d_in[5];
    const float* m1b  = (const float*)d_in[6];
    const float* c2w  = (const float*)d_in[7];
    const float* c2b  = (const float*)d_in[8];
    const float* m2Wx = (const float*)d_in[9];
    const float* m2Wl = (const float*)d_in[10];
    const float* m2Wu = (const float*)d_in[11];
    const float* m2b  = (const float*)d_in[12];
    const float* f1w  = (const float*)d_in[13];
    const float* f1b  = (const float*)d_in[14];
    const float* f2w  = (const float*)d_in[15];
    const float* f2b  = (const float*)d_in[16];
    float* outp = (float*)d_out;

    char* ws = (char*)d_ws;
    float* a1 = (float*)ws;                 // [B,144,10] 23.6 MB
    float* h1 = (float*)(ws + 23592960);    // [B,144,20] 47.2 MB
    float* a2 = a1;                         // [B,16,30] 7.86 MB (reuse a1)
    short* wfrag  = (short*)(ws + 8388608); // 102 KB (dead-a1 region, > a2)
    short* wfrag1 = (short*)(ws + 9437184); // 286 KB (dead-a1 region)
    float* h2 = h1;                         // [B,16,40] reuse

    conv1_pool_tanh<<<2304, 256, 0, stream>>>(x, c1w, c1b, a1);
    // m1: V=[x10|hl20|hu20] pad KV=64, NK=2, 7 M-tiles (112 rows)
    mdlstm_mfma<12, 12, 20, 10, 64, 2, 7, 136, 116><<<256, 448, 0, stream>>>(
        a1, m1Wx, m1Wl, m1Wu, m1b, h1);
    prep_conv2_frags<<<100, 256, 0, stream>>>(c2w, wfrag);    // a1 dead now
    prep_fc1_frags<<<560, 256, 0, stream>>>(f1w, wfrag1);
    conv2_mfma<<<256, 320, 0, stream>>>(h1, wfrag, c2b, a2);
    // m2: V=[x30|hl40|hu40] pad KV=128, NK=4, 13 M-tiles (208 rows)
    mdlstm_mfma<4, 4, 40, 30, 128, 4, 13, 264, 212><<<256, 832, 0, stream>>>(
        a2, m2Wx, m2Wl, m2Wu, m2b, h2);
    fc_fused<<<256, 448, 0, stream>>>(h2, wfrag1, f1b, f2w, f2b, outp);
}

// Round 9
// 227.195 us; speedup vs baseline: 3.1242x; 1.0028x over previous
//
#include <hip/hip_runtime.h>
#include <hip/hip_bf16.h>

typedef __attribute__((ext_vector_type(8))) short sh8;
typedef __attribute__((ext_vector_type(4))) float f4;
typedef unsigned short ushort_t;
typedef unsigned int uint_t;

// ---------- fast transcendentals (fp32) ----------
__device__ __forceinline__ float fast_rcp(float x) {
    return __builtin_amdgcn_rcpf(x);
}
__device__ __forceinline__ float sigmoidf_(float x) {
    return fast_rcp(1.f + __expf(-x));
}
__device__ __forceinline__ float tanhf_fast(float x) {
    float ax = fabsf(x);
    float e  = __expf(-2.f * ax);
    float t  = (1.f - e) * fast_rcp(1.f + e);
    return copysignf(t, x);
}

// ---------- bf16 split helpers (truncation; hi+lo ~ 2^-17 rel) ----------
__device__ __forceinline__ ushort_t bf16hi(float x) {
    return (ushort_t)(__float_as_uint(x) >> 16);
}
__device__ __forceinline__ float bf16tof(ushort_t u) {
    return __uint_as_float(((uint_t)u) << 16);
}

// ---------- conv1 (1->10, 5x5 VALID) + maxpool2 + tanh ----------
// x: [B,784] as 28x28, out COMPACT: [B,144,10]
__global__ __launch_bounds__(256) void conv1_pool_tanh(
    const float* __restrict__ x, const float* __restrict__ w,
    const float* __restrict__ bias, float* __restrict__ out)
{
    __shared__ float sw[250];
    __shared__ float sb[10];
    int t = threadIdx.x;
    if (t < 250) sw[t] = w[t];
    if (t < 10)  sb[t] = bias[t];
    __syncthreads();

    int gp  = blockIdx.x * 256 + t;
    int b   = gp / 144;
    int pix = gp % 144;
    int py = pix / 12, px = pix % 12;

    const float* img = x + (long)b * 784 + (2 * py) * 28 + 2 * px;
    float r[6][6];
#pragma unroll
    for (int ry = 0; ry < 6; ++ry)
#pragma unroll
        for (int rx = 0; rx < 6; ++rx)
            r[ry][rx] = img[ry * 28 + rx];

    float* ob = out + ((long)b * 144 + pix) * 10;
    for (int oc = 0; oc < 10; ++oc) {
        float a0 = 0.f, a1 = 0.f, a2 = 0.f, a3 = 0.f;
#pragma unroll
        for (int ky = 0; ky < 5; ++ky)
#pragma unroll
            for (int kx = 0; kx < 5; ++kx) {
                float wv = sw[oc * 25 + ky * 5 + kx];
                a0 += wv * r[ky][kx];
                a1 += wv * r[ky][kx + 1];
                a2 += wv * r[ky + 1][kx];
                a3 += wv * r[ky + 1][kx + 1];
            }
        float m = fmaxf(fmaxf(a0, a1), fmaxf(a2, a3)) + sb[oc];
        ob[oc] = tanhf_fast(m);
    }
}

// ---------- diagonal-wavefront MFMA 2D-LSTM ----------
// x compact [B, H*H, CIN]; Wx [5H,CIN], Whl/Whu [5H,HID], bias [5H];
// out compact [B, H*H, HID].  Block = 16 batch (grid 256), NW waves.
// Anti-diagonal d cells are independent; 2H-1 steps, 2 barriers/step.
// V per cell = [x(CIN) | hl(HID) | hu(HID) | pad] to KV, bf16 hi/lo zones.
// c-state double-buffered by diagonal parity.  Gate rows r: A-frag row
// r = wid*16+(lane&15), k = ks*32+(lane>>4)*8+e (layout proven in r3-r8).
template<int H, int HID, int CIN, int KV, int NK, int NW, int GS>
__global__ __launch_bounds__(NW * 64) void mdlstm_diag(
    const float* __restrict__ x, const float* __restrict__ Wx,
    const float* __restrict__ Whl, const float* __restrict__ Whu,
    const float* __restrict__ bias, float* __restrict__ out)
{
    constexpr int N    = H * H;
    constexpr int NT   = NW * 64;
    constexpr int HL0  = CIN, HU0 = CIN + HID;
    constexpr int SVS  = 2 * KV + 4;   // ushort stride: dword-stride % 32 == 2
    constexpr int XMAX = (H * 16 * CIN + NT - 1) / NT;
    static_assert(NW * 16 >= 5 * HID, "tiles cover gate rows");
    static_assert(KV >= CIN + 2 * HID, "K covers V");

    __shared__ ushort_t sV[H][16][SVS];      // per-slot: hi [0,KV), lo [KV,2KV)
    __shared__ float    sG[H][16][GS];       // gates: [slot][batch][row]
    __shared__ float    sC[2][H][16][HID];   // c-state, parity buffered

    const int tid  = threadIdx.x;
    const int lane = tid & 63;
    const int wid  = tid >> 6;
    const int lr   = lane & 15;
    const int lg   = lane >> 4;
    const int r    = wid * 16 + lr;
    const long bB  = (long)blockIdx.x * 16;

    // ---- A-frags via coalesced LDS staging (sG region as scratch) ----
    sh8 Ah[NK], Al[NK];
#pragma unroll
    for (int ks = 0; ks < NK; ++ks)
#pragma unroll
        for (int e = 0; e < 8; ++e) { Ah[ks][e] = 0; Al[ks][e] = 0; }

    float* praw = &sG[0][0][0];
    {   // round 1: Wx  (k in [0, CIN))
        for (int idx = tid; idx < 5 * HID * CIN; idx += NT) praw[idx] = Wx[idx];
        __syncthreads();
        if (r < 5 * HID) {
#pragma unroll
            for (int ks = 0; ks < NK; ++ks)
#pragma unroll
                for (int e = 0; e < 8; ++e) {
                    int k = ks * 32 + lg * 8 + e;
                    if (k < CIN) {
                        float wv = praw[r * CIN + k];
                        ushort_t hi = bf16hi(wv);
                        Ah[ks][e] = (short)hi;
                        Al[ks][e] = (short)bf16hi(wv - bf16tof(hi));
                    }
                }
        }
        __syncthreads();
    }
    {   // round 2: Whl (k in [HL0, HL0+HID))
        for (int idx = tid; idx < 5 * HID * HID; idx += NT) praw[idx] = Whl[idx];
        __syncthreads();
        if (r < 5 * HID) {
#pragma unroll
            for (int ks = 0; ks < NK; ++ks)
#pragma unroll
                for (int e = 0; e < 8; ++e) {
                    int kk = ks * 32 + lg * 8 + e - HL0;
                    if (kk >= 0 && kk < HID) {
                        float wv = praw[r * HID + kk];
                        ushort_t hi = bf16hi(wv);
                        Ah[ks][e] = (short)hi;
                        Al[ks][e] = (short)bf16hi(wv - bf16tof(hi));
                    }
                }
        }
        __syncthreads();
    }
    {   // round 3: Whu (k in [HU0, HU0+HID))
        for (int idx = tid; idx < 5 * HID * HID; idx += NT) praw[idx] = Whu[idx];
        __syncthreads();
        if (r < 5 * HID) {
#pragma unroll
            for (int ks = 0; ks < NK; ++ks)
#pragma unroll
                for (int e = 0; e < 8; ++e) {
                    int kk = ks * 32 + lg * 8 + e - HU0;
                    if (kk >= 0 && kk < HID) {
                        float wv = praw[r * HID + kk];
                        ushort_t hi = bf16hi(wv);
                        Ah[ks][e] = (short)hi;
                        Al[ks][e] = (short)bf16hi(wv - bf16tof(hi));
                    }
                }
        }
        __syncthreads();
    }

    f4 biasF;
#pragma unroll
    for (int q = 0; q < 4; ++q) {
        int rr = wid * 16 + lg * 4 + q;
        biasF[q] = (rr < 5 * HID) ? bias[rr] : 0.f;
    }

    // ---- zero sV; stage x for cell (0,0) ----
    for (int idx = tid; idx < H * 16 * SVS; idx += NT) (&sV[0][0][0])[idx] = 0;
    __syncthreads();
    for (int idx = tid; idx < 16 * CIN; idx += NT) {
        int b = idx / CIN, c = idx % CIN;
        float xv = x[(bB + b) * (long)(N * CIN) + c];
        ushort_t hi = bf16hi(xv);
        sV[0][b][c]      = hi;
        sV[0][b][KV + c] = bf16hi(xv - bf16tof(hi));
    }
    __syncthreads();

    // ---- diagonal loop ----
    for (int d = 0; d < 2 * H - 1; ++d) {
        const int i0  = (d > H - 1) ? d - (H - 1) : 0;
        const int i1  = (d < H - 1) ? d : H - 1;
        const int nc  = i1 - i0 + 1;
        const bool haveN = (d + 1 < 2 * H - 1);
        const int i0n = (d + 1 > H - 1) ? d + 1 - (H - 1) : 0;
        const int i1n = (d + 1 < H - 1) ? d + 1 : H - 1;
        const int ncn = haveN ? (i1n - i0n + 1) : 0;
        const int par = d & 1;

        // ===== Phase A: gates for all diagonal cells (MFMA) =====
        for (int ci = 0; ci < nc; ++ci) {
            sh8 Bh[NK], Bl[NK];
#pragma unroll
            for (int ks = 0; ks < NK; ++ks) {
                Bh[ks] = *(const sh8*)&sV[ci][lr][ks * 32 + lg * 8];
                Bl[ks] = *(const sh8*)&sV[ci][lr][KV + ks * 32 + lg * 8];
            }
            f4 acc = __builtin_amdgcn_mfma_f32_16x16x32_bf16(
                         Ah[0], Bh[0], biasF, 0, 0, 0);
#pragma unroll
            for (int ks = 1; ks < NK; ++ks)
                acc = __builtin_amdgcn_mfma_f32_16x16x32_bf16(
                          Ah[ks], Bh[ks], acc, 0, 0, 0);
#pragma unroll
            for (int ks = 0; ks < NK; ++ks)
                acc = __builtin_amdgcn_mfma_f32_16x16x32_bf16(
                          Ah[ks], Bl[ks], acc, 0, 0, 0);
#pragma unroll
            for (int ks = 0; ks < NK; ++ks)
                acc = __builtin_amdgcn_mfma_f32_16x16x32_bf16(
                          Al[ks], Bh[ks], acc, 0, 0, 0);
            if (wid * 16 + lg * 4 < GS)
                *(f4*)&sG[ci][lr][wid * 16 + lg * 4] = acc;
        }

        // prefetch next diagonal's x into registers (hides under MFMA)
        float xv[XMAX];
        const int xtot = ncn * 16 * CIN;
#pragma unroll
        for (int q = 0; q < XMAX; ++q) {
            int idx = tid + q * NT;
            if (idx < xtot) {
                int ci  = idx / (16 * CIN);
                int rem = idx % (16 * CIN);
                int b = rem / CIN, c = rem % CIN;
                int ii = i0n + ci, jj = d + 1 - ii;
                xv[q] = x[(bB + b) * (long)(N * CIN) + (ii * H + jj) * CIN + c];
            }
        }
        __syncthreads();

        // ===== Phase B: epilogue + scatter h into next-diag V =====
        for (int u = tid; u < nc * 16 * HID; u += NT) {
            int ci  = u / (16 * HID);
            int rem = u % (16 * HID);
            int b = rem / HID, j = rem % HID;
            int i = i0 + ci, jc = d - i;
            float g0 = sG[ci][b][0 * HID + j];
            float g1 = sG[ci][b][1 * HID + j];
            float g2 = sG[ci][b][2 * HID + j];
            float g3 = sG[ci][b][3 * HID + j];
            float g4 = sG[ci][b][4 * HID + j];
            float c_left = (jc > 0) ? sC[par][i][b][j] : 0.f;
            float c_up   = (i  > 0) ? sC[par][i - 1][b][j] : 0.f;
            float cc = sigmoidf_(g1) * c_left + sigmoidf_(g2) * c_up
                     + sigmoidf_(g0) * tanhf_fast(g4);
            float hh = sigmoidf_(g3) * tanhf_fast(cc);
            sC[par ^ 1][i][b][j] = cc;
            ushort_t hhi = bf16hi(hh);
            ushort_t hlo = bf16hi(hh - bf16tof(hhi));
            if (jc + 1 < H) {               // h_left for cell (i, jc+1)
                int sl = i - i0n;
                sV[sl][b][HL0 + j]      = hhi;
                sV[sl][b][KV + HL0 + j] = hlo;
            }
            if (i + 1 < H) {                // h_up for cell (i+1, jc)
                int su = i + 1 - i0n;
                sV[su][b][HU0 + j]      = hhi;
                sV[su][b][KV + HU0 + j] = hlo;
            }
            out[(bB + b) * (long)(N * HID) + (i * H + jc) * HID + j] = hh;
        }
        // write prefetched x into next-diag V slots
#pragma unroll
        for (int q = 0; q < XMAX; ++q) {
            int idx = tid + q * NT;
            if (idx < xtot) {
                int ci  = idx / (16 * CIN);
                int rem = idx % (16 * CIN);
                int b = rem / CIN, c = rem % CIN;
                ushort_t hi = bf16hi(xv[q]);
                sV[ci][b][c]      = hi;
                sV[ci][b][KV + c] = bf16hi(xv[q] - bf16tof(hi));
            }
        }
        __syncthreads();
    }
}

// ---------- prep: scatter conv2 weights into MFMA A-fragment layout ----------
__global__ __launch_bounds__(256) void prep_conv2_frags(
    const float* __restrict__ wt, short* __restrict__ wf)
{
    int id = blockIdx.x * 256 + threadIdx.x;   // over 25*2*64*8 = 25600
    if (id >= 25600) return;
    int e    = id & 7;
    int lane = (id >> 3) & 63;
    int m    = (id >> 9) & 1;
    int tt   = id >> 10;            // tx*5+ty
    int tx = tt / 5, ty = tt % 5;
    int c = lane & 15, kg = lane >> 4;
    int oc = m * 16 + c, ic = kg * 8 + e;
    float wv = (oc < 30 && ic < 20) ? wt[((oc * 20 + ic) * 5 + ty) * 5 + tx] : 0.f;
    ushort_t hi = bf16hi(wv);
    ushort_t lo = bf16hi(wv - bf16tof(hi));
    wf[(((tt * 2 + m) * 2 + 0) * 64 + lane) * 8 + e] = (short)hi;
    wf[(((tt * 2 + m) * 2 + 1) * 64 + lane) * 8 + e] = (short)lo;
}

// ---------- prep: scatter fc1 weights into MFMA A-fragment layout ----------
__global__ __launch_bounds__(256) void prep_fc1_frags(
    const float* __restrict__ w1, short* __restrict__ wf1)
{
    int id = blockIdx.x * 256 + threadIdx.x;   // over 7*20*2*64*8 = 143360
    if (id >= 143360) return;
    int e    = id & 7;
    int r    = id >> 3;
    int lane = r & 63;  r >>= 6;
    int h    = r & 1;   r >>= 1;
    int ks   = r % 20;
    int m    = r / 20;
    int o  = m * 16 + (lane & 15);
    int kp = ks * 32 + (lane >> 4) * 8 + e;
    int pix = kp / 40, hid = kp % 40;
    float wv = (o < 100) ? w1[o * 640 + hid * 16 + pix] : 0.f;
    ushort_t hi = bf16hi(wv);
    ushort_t v  = h ? (ushort_t)bf16hi(wv - bf16tof(hi)) : hi;
    wf1[id] = (short)v;
}

// ---------- conv2 stage helper: one float4 (4 channels of one pos) ----------
__device__ __forceinline__ void stage_f4(
    ushort_t (*Hi)[40], ushort_t (*Lo)[40], int f, float4 v)
{
    int pos = f / 5, q = f % 5;
    ushort_t h0 = bf16hi(v.x), h1 = bf16hi(v.y);
    ushort_t h2 = bf16hi(v.z), h3 = bf16hi(v.w);
    ushort_t l0 = bf16hi(v.x - bf16tof(h0));
    ushort_t l1 = bf16hi(v.y - bf16tof(h1));
    ushort_t l2 = bf16hi(v.z - bf16tof(h2));
    ushort_t l3 = bf16hi(v.w - bf16tof(h3));
    uint2 hp = { (uint_t)h0 | ((uint_t)h1 << 16), (uint_t)h2 | ((uint_t)h3 << 16) };
    uint2 lp = { (uint_t)l0 | ((uint_t)l1 << 16), (uint_t)l2 | ((uint_t)l3 << 16) };
    *(uint2*)&Hi[pos][q * 4] = hp;
    *(uint2*)&Lo[pos][q * 4] = lp;
}

// ---------- conv2 via tap-decomposed MFMA, 16 images/block ----------
__global__ __launch_bounds__(320, 2) void conv2_mfma(
    const float* __restrict__ in, const short* __restrict__ wf,
    const float* __restrict__ bias, float* __restrict__ out)
{
    constexpr int NIMG = 16;
    __shared__ ushort_t sHi[2][144][40];
    __shared__ ushort_t sLo[2][144][40];
    __shared__ float    sPart[5][2][4][16][20];
    __shared__ float    sB[30];

    const int tid  = threadIdx.x;
    const int lane = tid & 63;
    const int wid  = tid >> 6;          // = tx
    const int c    = lane & 15;
    const int kg   = lane >> 4;
    const long b0  = (long)blockIdx.x * NIMG;

    const sh8* wfv = (const sh8*)wf;
    sh8 Ah[5][2], Al[5][2];
#pragma unroll
    for (int ty = 0; ty < 5; ++ty)
#pragma unroll
        for (int m = 0; m < 2; ++m) {
            int base = (((wid * 5 + ty) * 2 + m) * 2) * 64 + lane;
            Ah[ty][m] = wfv[base];
            Al[ty][m] = wfv[base + 64];
        }

    for (int idx = tid; idx < 2 * 144 * 20; idx += 320) {
        int bb = idx / (144 * 20);
        int r  = idx % (144 * 20);
        int pos = r / 20, s = 20 + r % 20;
        sHi[bb][pos][s] = 0;
        sLo[bb][pos][s] = 0;
    }
    if (tid < 30) sB[tid] = bias[tid];

    {
        const float* p = in + b0 * 2880;
        float4 v0 = *(const float4*)(p + 4 * tid);
        float4 v1 = *(const float4*)(p + 4 * (tid + 320));
        float4 v2 = {0.f, 0.f, 0.f, 0.f};
        if (tid < 80) v2 = *(const float4*)(p + 4 * (tid + 640));
        stage_f4(sHi[0], sLo[0], tid, v0);
        stage_f4(sHi[0], sLo[0], tid + 320, v1);
        if (tid < 80) stage_f4(sHi[0], sLo[0], tid + 640, v2);
    }
    __syncthreads();

    const int y0 = c >> 3, x = c & 7;
    for (int img = 0; img < NIMG; ++img) {
        const int cb = img & 1;
        float4 v0, v1, v2;
        const bool have = (img + 1 < NIMG);
        if (have) {
            const float* p = in + (b0 + img + 1) * 2880;
            v0 = *(const float4*)(p + 4 * tid);
            v1 = *(const float4*)(p + 4 * (tid + 320));
            if (tid < 80) v2 = *(const float4*)(p + 4 * (tid + 640));
        }
#pragma unroll
        for (int p4 = 0; p4 < 4; ++p4) {
            const int pos = (2 * p4 + y0) * 12 + x + wid;
            const ushort_t* bh = &sHi[cb][pos][kg * 8];
            const ushort_t* bl = &sLo[cb][pos][kg * 8];
            f4 hh0 = {0.f,0.f,0.f,0.f}, hl0 = {0.f,0.f,0.f,0.f}, lh0 = {0.f,0.f,0.f,0.f};
            f4 hh1 = {0.f,0.f,0.f,0.f}, hl1 = {0.f,0.f,0.f,0.f}, lh1 = {0.f,0.f,0.f,0.f};
#pragma unroll
            for (int ks = 0; ks < 5; ++ks) {
                sh8 Bh = *(const sh8*)(bh + ks * 12 * 40);
                sh8 Bl = *(const sh8*)(bl + ks * 12 * 40);
                hh0 = __builtin_amdgcn_mfma_f32_16x16x32_bf16(Ah[ks][0], Bh, hh0, 0, 0, 0);
                hl0 = __builtin_amdgcn_mfma_f32_16x16x32_bf16(Ah[ks][0], Bl, hl0, 0, 0, 0);
                lh0 = __builtin_amdgcn_mfma_f32_16x16x32_bf16(Al[ks][0], Bh, lh0, 0, 0, 0);
                hh1 = __builtin_amdgcn_mfma_f32_16x16x32_bf16(Ah[ks][1], Bh, hh1, 0, 0, 0);
                hl1 = __builtin_amdgcn_mfma_f32_16x16x32_bf16(Ah[ks][1], Bl, hl1, 0, 0, 0);
                lh1 = __builtin_amdgcn_mfma_f32_16x16x32_bf16(Al[ks][1], Bh, lh1, 0, 0, 0);
            }
            f4 c0 = hh0 + hl0 + lh0;
            f4 c1 = hh1 + hl1 + lh1;
            *(f4*)&sPart[wid][0][p4][c][kg * 4] = c0;
            *(f4*)&sPart[wid][1][p4][c][kg * 4] = c1;
        }
        if (have) {
            stage_f4(sHi[cb ^ 1], sLo[cb ^ 1], tid, v0);
            stage_f4(sHi[cb ^ 1], sLo[cb ^ 1], tid + 320, v1);
            if (tid < 80) stage_f4(sHi[cb ^ 1], sLo[cb ^ 1], tid + 640, v2);
        }
        __syncthreads();
        for (int idx = tid; idx < 480; idx += 320) {
            int pix = idx / 30, oc = idx % 30;
            int m = oc >> 4, r = oc & 15;
            int py = pix >> 2, px = pix & 3;
            float vmax = -1e30f;
#pragma unroll
            for (int dy = 0; dy < 2; ++dy)
#pragma unroll
                for (int dx = 0; dx < 2; ++dx) {
                    int n = (2 * py + dy) * 8 + 2 * px + dx;
                    float s = 0.f;
#pragma unroll
                    for (int w = 0; w < 5; ++w)
                        s += sPart[w][m][n >> 4][n & 15][r];
                    vmax = fmaxf(vmax, s);
                }
            out[(b0 + img) * 480 + idx] = tanhf_fast(vmax + sB[oc]);
        }
        __syncthreads();
    }
}

// ---------- fused fc1(640->100)+tanh + fc2(100->10) + softmax ----------
__global__ __launch_bounds__(448) void fc_fused(
    const float* __restrict__ in, const short* __restrict__ wf1,
    const float* __restrict__ b1, const float* __restrict__ w2,
    const float* __restrict__ b2, float* __restrict__ out)
{
    constexpr int XS = 648;      // padded row stride (ushorts)
    __shared__ ushort_t sXh[16][XS];
    __shared__ ushort_t sXl[16][XS];
    __shared__ float    sG[16][116];
    __shared__ float    sF[16][101];
    __shared__ float    sW2[1000];
    __shared__ float    sB2[10];
    __shared__ float    sL[16][12];

    const int tid  = threadIdx.x;
    const int lane = tid & 63;
    const int wid  = tid >> 6;
    const int lr   = lane & 15;
    const int lg   = lane >> 4;
    const long b0  = (long)blockIdx.x * 16;

    for (int idx = tid; idx < 2560; idx += 448) {
        int flat = idx * 4;
        int row = flat / 640, col = flat % 640;
        float4 v = *(const float4*)(in + (b0 + row) * 640 + col);
        ushort_t h0 = bf16hi(v.x), h1 = bf16hi(v.y);
        ushort_t h2 = bf16hi(v.z), h3 = bf16hi(v.w);
        uint2 hp = { (uint_t)h0 | ((uint_t)h1 << 16), (uint_t)h2 | ((uint_t)h3 << 16) };
        ushort_t l0 = bf16hi(v.x - bf16tof(h0));
        ushort_t l1 = bf16hi(v.y - bf16tof(h1));
        ushort_t l2 = bf16hi(v.z - bf16tof(h2));
        ushort_t l3 = bf16hi(v.w - bf16tof(h3));
        uint2 lp = { (uint_t)l0 | ((uint_t)l1 << 16), (uint_t)l2 | ((uint_t)l3 << 16) };
        *(uint2*)&sXh[row][col] = hp;
        *(uint2*)&sXl[row][col] = lp;
    }
    for (int idx = tid; idx < 1000; idx += 448) sW2[idx] = w2[idx];
    if (tid < 10) sB2[tid] = b2[tid];

    f4 biasF;
#pragma unroll
    for (int q = 0; q < 4; ++q) {
        int rr = wid * 16 + lg * 4 + q;
        biasF[q] = (rr < 100) ? b1[rr] : 0.f;
    }
    __syncthreads();

    {
        const sh8* wfv = (const sh8*)wf1;
        f4 hh = biasF, hl = {0.f,0.f,0.f,0.f}, lh = {0.f,0.f,0.f,0.f};
#pragma unroll
        for (int ks = 0; ks < 20; ++ks) {
            int base = ((wid * 20 + ks) * 2) * 64 + lane;
            sh8 Ah = wfv[base];
            sh8 Al = wfv[base + 64];
            sh8 Bh = *(const sh8*)&sXh[lr][ks * 32 + lg * 8];
            sh8 Bl = *(const sh8*)&sXl[lr][ks * 32 + lg * 8];
            hh = __builtin_amdgcn_mfma_f32_16x16x32_bf16(Ah, Bh, hh, 0, 0, 0);
            hl = __builtin_amdgcn_mfma_f32_16x16x32_bf16(Ah, Bl, hl, 0, 0, 0);
            lh = __builtin_amdgcn_mfma_f32_16x16x32_bf16(Al, Bh, lh, 0, 0, 0);
        }
        f4 acc = hh + hl + lh;
        *(f4*)&sG[lr][wid * 16 + lg * 4] = acc;
    }
    __syncthreads();

    for (int idx = tid; idx < 1600; idx += 448) {
        int bb = idx / 100, o = idx % 100;
        sF[bb][o] = tanhf_fast(sG[bb][o]);
    }
    __syncthreads();

    if (tid < 160) {
        int o2 = tid >> 4, bb = tid & 15;
        const float* wr = &sW2[o2 * 100];
        float acc = sB2[o2];
        for (int k = 0; k < 100; ++k) acc += sF[bb][k] * wr[k];
        sL[bb][o2] = acc;
    }
    __syncthreads();

    if (tid < 16) {
        float lg10[10];
#pragma unroll
        for (int o = 0; o < 10; ++o) lg10[o] = sL[tid][o];
        float m = lg10[0];
#pragma unroll
        for (int o = 1; o < 10; ++o) m = fmaxf(m, lg10[o]);
        float s = 0.f;
#pragma unroll
        for (int o = 0; o < 10; ++o) { lg10[o] = __expf(lg10[o] - m); s += lg10[o]; }
        float inv = fast_rcp(s);
        float* ob = out + (b0 + tid) * 10;
#pragma unroll
        for (int o = 0; o < 10; ++o) ob[o] = lg10[o] * inv;
    }
}

extern "C" void kernel_launch(void* const* d_in, const int* in_sizes, int n_in,
                              void* d_out, int out_size, void* d_ws, size_t ws_size,
                              hipStream_t stream)
{
    const float* x    = (const float*)d_in[0];
    const float* c1w  = (const float*)d_in[1];
    const float* c1b  = (const float*)d_in[2];
    const float* m1Wx = (const float*)d_in[3];
    const float* m1Wl = (const float*)d_in[4];
    const float* m1Wu = (const float*)d_in[5];
    const float* m1b  = (const float*)d_in[6];
    const float* c2w  = (const float*)d_in[7];
    const float* c2b  = (const float*)d_in[8];
    const float* m2Wx = (const float*)d_in[9];
    const float* m2Wl = (const float*)d_in[10];
    const float* m2Wu = (const float*)d_in[11];
    const float* m2b  = (const float*)d_in[12];
    const float* f1w  = (const float*)d_in[13];
    const float* f1b  = (const float*)d_in[14];
    const float* f2w  = (const float*)d_in[15];
    const float* f2b  = (const float*)d_in[16];
    float* outp = (float*)d_out;

    char* ws = (char*)d_ws;
    float* a1 = (float*)ws;                 // [B,144,10] 23.6 MB
    float* h1 = (float*)(ws + 23592960);    // [B,144,20] 47.2 MB
    float* a2 = a1;                         // [B,16,30] 7.86 MB (reuse a1)
    short* wfrag  = (short*)(ws + 8388608); // 102 KB (dead-a1 region, > a2)
    short* wfrag1 = (short*)(ws + 9437184); // 286 KB (dead-a1 region)
    float* h2 = h1;                         // [B,16,40] reuse

    conv1_pool_tanh<<<2304, 256, 0, stream>>>(x, c1w, c1b, a1);
    // m1: H=12, HID=20, CIN=10, KV=64, NK=2, NW=7, GS=104
    mdlstm_diag<12, 20, 10, 64, 2, 7, 104><<<256, 448, 0, stream>>>(
        a1, m1Wx, m1Wl, m1Wu, m1b, h1);
    prep_conv2_frags<<<100, 256, 0, stream>>>(c2w, wfrag);    // a1 dead now
    prep_fc1_frags<<<560, 256, 0, stream>>>(f1w, wfrag1);
    conv2_mfma<<<256, 320, 0, stream>>>(h1, wfrag, c2b, a2);
    // m2: H=4, HID=40, CIN=30, KV=128, NK=4, NW=13, GS=212
    mdlstm_diag<4, 40, 30, 128, 4, 13, 212><<<256, 832, 0, stream>>>(
        a2, m2Wx, m2Wl, m2Wu, m2b, h2);
    fc_fused<<<256, 448, 0, stream>>>(h2, wfrag1, f1b, f2w, f2b, outp);
}

// Round 10
// 205.521 us; speedup vs baseline: 3.4537x; 1.1055x over previous
//
#include <hip/hip_runtime.h>
#include <hip/hip_bf16.h>

typedef __attribute__((ext_vector_type(8))) short sh8;
typedef __attribute__((ext_vector_type(4))) float f4;
typedef unsigned short ushort_t;
typedef unsigned int uint_t;

// ---------- fast transcendentals (fp32) ----------
__device__ __forceinline__ float fast_rcp(float x) {
    return __builtin_amdgcn_rcpf(x);
}
__device__ __forceinline__ float sigmoidf_(float x) {
    return fast_rcp(1.f + __expf(-x));
}
__device__ __forceinline__ float tanhf_fast(float x) {
    float ax = fabsf(x);
    float e  = __expf(-2.f * ax);
    float t  = (1.f - e) * fast_rcp(1.f + e);
    return copysignf(t, x);
}

// ---------- bf16 split helpers (truncation; hi+lo ~ 2^-17 rel) ----------
__device__ __forceinline__ ushort_t bf16hi(float x) {
    return (ushort_t)(__float_as_uint(x) >> 16);
}
__device__ __forceinline__ float bf16tof(ushort_t u) {
    return __uint_as_float(((uint_t)u) << 16);
}

// ---------- conv1 (1->10, 5x5 VALID) + maxpool2 + tanh ----------
// x: [B,784] as 28x28, out COMPACT: [B,144,10]
__global__ __launch_bounds__(256) void conv1_pool_tanh(
    const float* __restrict__ x, const float* __restrict__ w,
    const float* __restrict__ bias, float* __restrict__ out)
{
    __shared__ float sw[250];
    __shared__ float sb[10];
    int t = threadIdx.x;
    if (t < 250) sw[t] = w[t];
    if (t < 10)  sb[t] = bias[t];
    __syncthreads();

    int gp  = blockIdx.x * 256 + t;
    int b   = gp / 144;
    int pix = gp % 144;
    int py = pix / 12, px = pix % 12;

    const float* img = x + (long)b * 784 + (2 * py) * 28 + 2 * px;
    float r[6][6];
#pragma unroll
    for (int ry = 0; ry < 6; ++ry)
#pragma unroll
        for (int rx = 0; rx < 6; ++rx)
            r[ry][rx] = img[ry * 28 + rx];

    float* ob = out + ((long)b * 144 + pix) * 10;
    for (int oc = 0; oc < 10; ++oc) {
        float a0 = 0.f, a1 = 0.f, a2 = 0.f, a3 = 0.f;
#pragma unroll
        for (int ky = 0; ky < 5; ++ky)
#pragma unroll
            for (int kx = 0; kx < 5; ++kx) {
                float wv = sw[oc * 25 + ky * 5 + kx];
                a0 += wv * r[ky][kx];
                a1 += wv * r[ky][kx + 1];
                a2 += wv * r[ky + 1][kx];
                a3 += wv * r[ky + 1][kx + 1];
            }
        float m = fmaxf(fmaxf(a0, a1), fmaxf(a2, a3)) + sb[oc];
        ob[oc] = tanhf_fast(m);
    }
}

// ---------- diagonal-wavefront MFMA 2D-LSTM, cell-split waves ----------
// x compact [B, H*H, CIN]; Wx [5H,CIN], Whl/Whu [5H,HID], bias [5H];
// out compact [B, H*H, HID].  Block = 16 batch (grid 256).
// NWM M-tile waves x CSPL cell-groups; wave (mt, cs) processes diagonal
// cells ci == cs (mod CSPL) for gate rows [16mt, 16mt+16).
// 2H-1 steps, 2 barriers/step; c-state parity double-buffered.
template<int H, int HID, int CIN, int KV, int NK, int NWM, int CSPL, int GS>
__global__ __launch_bounds__(NWM * CSPL * 64) void mdlstm_diag(
    const float* __restrict__ x, const float* __restrict__ Wx,
    const float* __restrict__ Whl, const float* __restrict__ Whu,
    const float* __restrict__ bias, float* __restrict__ out)
{
    constexpr int N    = H * H;
    constexpr int NT   = NWM * CSPL * 64;
    constexpr int HL0  = CIN, HU0 = CIN + HID;
    constexpr int SVS  = 2 * KV + 4;   // ushort stride: dword-stride % 32 == 2
    constexpr int XMAX = (H * 16 * CIN + NT - 1) / NT;
    static_assert(NWM * 16 >= 5 * HID, "tiles cover gate rows");
    static_assert(KV >= CIN + 2 * HID, "K covers V");

    __shared__ ushort_t sV[H][16][SVS];      // per-slot: hi [0,KV), lo [KV,2KV)
    __shared__ float    sG[H][16][GS];       // gates: [slot][batch][row]
    __shared__ float    sC[2][H][16][HID];   // c-state, parity buffered

    const int tid  = threadIdx.x;
    const int lane = tid & 63;
    const int wid  = tid >> 6;
    const int mt   = wid % NWM;              // M-tile
    const int cs   = wid / NWM;              // cell-parity group
    const int lr   = lane & 15;
    const int lg   = lane >> 4;
    const int r    = mt * 16 + lr;
    const long bB  = (long)blockIdx.x * 16;

    // ---- A-frags via coalesced LDS staging (sG region as scratch) ----
    sh8 Ah[NK], Al[NK];
#pragma unroll
    for (int ks = 0; ks < NK; ++ks)
#pragma unroll
        for (int e = 0; e < 8; ++e) { Ah[ks][e] = 0; Al[ks][e] = 0; }

    float* praw = &sG[0][0][0];
    {   // round 1: Wx  (k in [0, CIN))
        for (int idx = tid; idx < 5 * HID * CIN; idx += NT) praw[idx] = Wx[idx];
        __syncthreads();
        if (r < 5 * HID) {
#pragma unroll
            for (int ks = 0; ks < NK; ++ks)
#pragma unroll
                for (int e = 0; e < 8; ++e) {
                    int k = ks * 32 + lg * 8 + e;
                    if (k < CIN) {
                        float wv = praw[r * CIN + k];
                        ushort_t hi = bf16hi(wv);
                        Ah[ks][e] = (short)hi;
                        Al[ks][e] = (short)bf16hi(wv - bf16tof(hi));
                    }
                }
        }
        __syncthreads();
    }
    {   // round 2: Whl (k in [HL0, HL0+HID))
        for (int idx = tid; idx < 5 * HID * HID; idx += NT) praw[idx] = Whl[idx];
        __syncthreads();
        if (r < 5 * HID) {
#pragma unroll
            for (int ks = 0; ks < NK; ++ks)
#pragma unroll
                for (int e = 0; e < 8; ++e) {
                    int kk = ks * 32 + lg * 8 + e - HL0;
                    if (kk >= 0 && kk < HID) {
                        float wv = praw[r * HID + kk];
                        ushort_t hi = bf16hi(wv);
                        Ah[ks][e] = (short)hi;
                        Al[ks][e] = (short)bf16hi(wv - bf16tof(hi));
                    }
                }
        }
        __syncthreads();
    }
    {   // round 3: Whu (k in [HU0, HU0+HID))
        for (int idx = tid; idx < 5 * HID * HID; idx += NT) praw[idx] = Whu[idx];
        __syncthreads();
        if (r < 5 * HID) {
#pragma unroll
            for (int ks = 0; ks < NK; ++ks)
#pragma unroll
                for (int e = 0; e < 8; ++e) {
                    int kk = ks * 32 + lg * 8 + e - HU0;
                    if (kk >= 0 && kk < HID) {
                        float wv = praw[r * HID + kk];
                        ushort_t hi = bf16hi(wv);
                        Ah[ks][e] = (short)hi;
                        Al[ks][e] = (short)bf16hi(wv - bf16tof(hi));
                    }
                }
        }
        __syncthreads();
    }

    f4 biasF;
#pragma unroll
    for (int q = 0; q < 4; ++q) {
        int rr = mt * 16 + lg * 4 + q;
        biasF[q] = (rr < 5 * HID) ? bias[rr] : 0.f;
    }

    // ---- zero sV; stage x for cell (0,0) ----
    for (int idx = tid; idx < H * 16 * SVS; idx += NT) (&sV[0][0][0])[idx] = 0;
    __syncthreads();
    for (int idx = tid; idx < 16 * CIN; idx += NT) {
        int b = idx / CIN, c = idx % CIN;
        float xv = x[(bB + b) * (long)(N * CIN) + c];
        ushort_t hi = bf16hi(xv);
        sV[0][b][c]      = hi;
        sV[0][b][KV + c] = bf16hi(xv - bf16tof(hi));
    }
    __syncthreads();

    // ---- diagonal loop ----
    for (int d = 0; d < 2 * H - 1; ++d) {
        const int i0  = (d > H - 1) ? d - (H - 1) : 0;
        const int i1  = (d < H - 1) ? d : H - 1;
        const int nc  = i1 - i0 + 1;
        const bool haveN = (d + 1 < 2 * H - 1);
        const int i0n = (d + 1 > H - 1) ? d + 1 - (H - 1) : 0;
        const int i1n = (d + 1 < H - 1) ? d + 1 : H - 1;
        const int ncn = haveN ? (i1n - i0n + 1) : 0;
        const int par = d & 1;

        // ===== Phase A: gates; wave-group cs handles cells ci%CSPL==cs =====
        for (int ci = cs; ci < nc; ci += CSPL) {
            sh8 Bh[NK], Bl[NK];
#pragma unroll
            for (int ks = 0; ks < NK; ++ks) {
                Bh[ks] = *(const sh8*)&sV[ci][lr][ks * 32 + lg * 8];
                Bl[ks] = *(const sh8*)&sV[ci][lr][KV + ks * 32 + lg * 8];
            }
            f4 acc = __builtin_amdgcn_mfma_f32_16x16x32_bf16(
                         Ah[0], Bh[0], biasF, 0, 0, 0);
#pragma unroll
            for (int ks = 1; ks < NK; ++ks)
                acc = __builtin_amdgcn_mfma_f32_16x16x32_bf16(
                          Ah[ks], Bh[ks], acc, 0, 0, 0);
#pragma unroll
            for (int ks = 0; ks < NK; ++ks)
                acc = __builtin_amdgcn_mfma_f32_16x16x32_bf16(
                          Ah[ks], Bl[ks], acc, 0, 0, 0);
#pragma unroll
            for (int ks = 0; ks < NK; ++ks)
                acc = __builtin_amdgcn_mfma_f32_16x16x32_bf16(
                          Al[ks], Bh[ks], acc, 0, 0, 0);
            if (mt * 16 + lg * 4 < GS)
                *(f4*)&sG[ci][lr][mt * 16 + lg * 4] = acc;
        }

        // prefetch next diagonal's x into registers (hides under MFMA)
        float xv[XMAX];
        const int xtot = ncn * 16 * CIN;
#pragma unroll
        for (int q = 0; q < XMAX; ++q) {
            int idx = tid + q * NT;
            if (idx < xtot) {
                int ci  = idx / (16 * CIN);
                int rem = idx % (16 * CIN);
                int b = rem / CIN, c = rem % CIN;
                int ii = i0n + ci, jj = d + 1 - ii;
                xv[q] = x[(bB + b) * (long)(N * CIN) + (ii * H + jj) * CIN + c];
            }
        }
        __syncthreads();

        // ===== Phase B: epilogue + scatter h into next-diag V =====
        for (int u = tid; u < nc * 16 * HID; u += NT) {
            int ci  = u / (16 * HID);
            int rem = u % (16 * HID);
            int b = rem / HID, j = rem % HID;
            int i = i0 + ci, jc = d - i;
            float g0 = sG[ci][b][0 * HID + j];
            float g1 = sG[ci][b][1 * HID + j];
            float g2 = sG[ci][b][2 * HID + j];
            float g3 = sG[ci][b][3 * HID + j];
            float g4 = sG[ci][b][4 * HID + j];
            float c_left = (jc > 0) ? sC[par][i][b][j] : 0.f;
            float c_up   = (i  > 0) ? sC[par][i - 1][b][j] : 0.f;
            float cc = sigmoidf_(g1) * c_left + sigmoidf_(g2) * c_up
                     + sigmoidf_(g0) * tanhf_fast(g4);
            float hh = sigmoidf_(g3) * tanhf_fast(cc);
            sC[par ^ 1][i][b][j] = cc;
            ushort_t hhi = bf16hi(hh);
            ushort_t hlo = bf16hi(hh - bf16tof(hhi));
            if (jc + 1 < H) {               // h_left for cell (i, jc+1)
                int sl = i - i0n;
                sV[sl][b][HL0 + j]      = hhi;
                sV[sl][b][KV + HL0 + j] = hlo;
            }
            if (i + 1 < H) {                // h_up for cell (i+1, jc)
                int su = i + 1 - i0n;
                sV[su][b][HU0 + j]      = hhi;
                sV[su][b][KV + HU0 + j] = hlo;
            }
            out[(bB + b) * (long)(N * HID) + (i * H + jc) * HID + j] = hh;
        }
        // write prefetched x into next-diag V slots
#pragma unroll
        for (int q = 0; q < XMAX; ++q) {
            int idx = tid + q * NT;
            if (idx < xtot) {
                int ci  = idx / (16 * CIN);
                int rem = idx % (16 * CIN);
                int b = rem / CIN, c = rem % CIN;
                ushort_t hi = bf16hi(xv[q]);
                sV[ci][b][c]      = hi;
                sV[ci][b][KV + c] = bf16hi(xv[q] - bf16tof(hi));
            }
        }
        __syncthreads();
    }
}

// ---------- prep: scatter conv2 weights into MFMA A-fragment layout ----------
__global__ __launch_bounds__(256) void prep_conv2_frags(
    const float* __restrict__ wt, short* __restrict__ wf)
{
    int id = blockIdx.x * 256 + threadIdx.x;   // over 25*2*64*8 = 25600
    if (id >= 25600) return;
    int e    = id & 7;
    int lane = (id >> 3) & 63;
    int m    = (id >> 9) & 1;
    int tt   = id >> 10;            // tx*5+ty
    int tx = tt / 5, ty = tt % 5;
    int c = lane & 15, kg = lane >> 4;
    int oc = m * 16 + c, ic = kg * 8 + e;
    float wv = (oc < 30 && ic < 20) ? wt[((oc * 20 + ic) * 5 + ty) * 5 + tx] : 0.f;
    ushort_t hi = bf16hi(wv);
    ushort_t lo = bf16hi(wv - bf16tof(hi));
    wf[(((tt * 2 + m) * 2 + 0) * 64 + lane) * 8 + e] = (short)hi;
    wf[(((tt * 2 + m) * 2 + 1) * 64 + lane) * 8 + e] = (short)lo;
}

// ---------- prep: scatter fc1 weights into MFMA A-fragment layout ----------
__global__ __launch_bounds__(256) void prep_fc1_frags(
    const float* __restrict__ w1, short* __restrict__ wf1)
{
    int id = blockIdx.x * 256 + threadIdx.x;   // over 7*20*2*64*8 = 143360
    if (id >= 143360) return;
    int e    = id & 7;
    int r    = id >> 3;
    int lane = r & 63;  r >>= 6;
    int h    = r & 1;   r >>= 1;
    int ks   = r % 20;
    int m    = r / 20;
    int o  = m * 16 + (lane & 15);
    int kp = ks * 32 + (lane >> 4) * 8 + e;
    int pix = kp / 40, hid = kp % 40;
    float wv = (o < 100) ? w1[o * 640 + hid * 16 + pix] : 0.f;
    ushort_t hi = bf16hi(wv);
    ushort_t v  = h ? (ushort_t)bf16hi(wv - bf16tof(hi)) : hi;
    wf1[id] = (short)v;
}

// ---------- conv2 stage helper: one float4 (4 channels of one pos) ----------
__device__ __forceinline__ void stage_f4(
    ushort_t (*Hi)[40], ushort_t (*Lo)[40], int f, float4 v)
{
    int pos = f / 5, q = f % 5;
    ushort_t h0 = bf16hi(v.x), h1 = bf16hi(v.y);
    ushort_t h2 = bf16hi(v.z), h3 = bf16hi(v.w);
    ushort_t l0 = bf16hi(v.x - bf16tof(h0));
    ushort_t l1 = bf16hi(v.y - bf16tof(h1));
    ushort_t l2 = bf16hi(v.z - bf16tof(h2));
    ushort_t l3 = bf16hi(v.w - bf16tof(h3));
    uint2 hp = { (uint_t)h0 | ((uint_t)h1 << 16), (uint_t)h2 | ((uint_t)h3 << 16) };
    uint2 lp = { (uint_t)l0 | ((uint_t)l1 << 16), (uint_t)l2 | ((uint_t)l3 << 16) };
    *(uint2*)&Hi[pos][q * 4] = hp;
    *(uint2*)&Lo[pos][q * 4] = lp;
}

// ---------- conv2 via tap-decomposed MFMA, 16 images/block ----------
__global__ __launch_bounds__(320, 2) void conv2_mfma(
    const float* __restrict__ in, const short* __restrict__ wf,
    const float* __restrict__ bias, float* __restrict__ out)
{
    constexpr int NIMG = 16;
    __shared__ ushort_t sHi[2][144][40];
    __shared__ ushort_t sLo[2][144][40];
    __shared__ float    sPart[5][2][4][16][20];
    __shared__ float    sB[30];

    const int tid  = threadIdx.x;
    const int lane = tid & 63;
    const int wid  = tid >> 6;          // = tx
    const int c    = lane & 15;
    const int kg   = lane >> 4;
    const long b0  = (long)blockIdx.x * NIMG;

    const sh8* wfv = (const sh8*)wf;
    sh8 Ah[5][2], Al[5][2];
#pragma unroll
    for (int ty = 0; ty < 5; ++ty)
#pragma unroll
        for (int m = 0; m < 2; ++m) {
            int base = (((wid * 5 + ty) * 2 + m) * 2) * 64 + lane;
            Ah[ty][m] = wfv[base];
            Al[ty][m] = wfv[base + 64];
        }

    for (int idx = tid; idx < 2 * 144 * 20; idx += 320) {
        int bb = idx / (144 * 20);
        int r  = idx % (144 * 20);
        int pos = r / 20, s = 20 + r % 20;
        sHi[bb][pos][s] = 0;
        sLo[bb][pos][s] = 0;
    }
    if (tid < 30) sB[tid] = bias[tid];

    {
        const float* p = in + b0 * 2880;
        float4 v0 = *(const float4*)(p + 4 * tid);
        float4 v1 = *(const float4*)(p + 4 * (tid + 320));
        float4 v2 = {0.f, 0.f, 0.f, 0.f};
        if (tid < 80) v2 = *(const float4*)(p + 4 * (tid + 640));
        stage_f4(sHi[0], sLo[0], tid, v0);
        stage_f4(sHi[0], sLo[0], tid + 320, v1);
        if (tid < 80) stage_f4(sHi[0], sLo[0], tid + 640, v2);
    }
    __syncthreads();

    const int y0 = c >> 3, x = c & 7;
    for (int img = 0; img < NIMG; ++img) {
        const int cb = img & 1;
        float4 v0, v1, v2;
        const bool have = (img + 1 < NIMG);
        if (have) {
            const float* p = in + (b0 + img + 1) * 2880;
            v0 = *(const float4*)(p + 4 * tid);
            v1 = *(const float4*)(p + 4 * (tid + 320));
            if (tid < 80) v2 = *(const float4*)(p + 4 * (tid + 640));
        }
#pragma unroll
        for (int p4 = 0; p4 < 4; ++p4) {
            const int pos = (2 * p4 + y0) * 12 + x + wid;
            const ushort_t* bh = &sHi[cb][pos][kg * 8];
            const ushort_t* bl = &sLo[cb][pos][kg * 8];
            f4 hh0 = {0.f,0.f,0.f,0.f}, hl0 = {0.f,0.f,0.f,0.f}, lh0 = {0.f,0.f,0.f,0.f};
            f4 hh1 = {0.f,0.f,0.f,0.f}, hl1 = {0.f,0.f,0.f,0.f}, lh1 = {0.f,0.f,0.f,0.f};
#pragma unroll
            for (int ks = 0; ks < 5; ++ks) {
                sh8 Bh = *(const sh8*)(bh + ks * 12 * 40);
                sh8 Bl = *(const sh8*)(bl + ks * 12 * 40);
                hh0 = __builtin_amdgcn_mfma_f32_16x16x32_bf16(Ah[ks][0], Bh, hh0, 0, 0, 0);
                hl0 = __builtin_amdgcn_mfma_f32_16x16x32_bf16(Ah[ks][0], Bl, hl0, 0, 0, 0);
                lh0 = __builtin_amdgcn_mfma_f32_16x16x32_bf16(Al[ks][0], Bh, lh0, 0, 0, 0);
                hh1 = __builtin_amdgcn_mfma_f32_16x16x32_bf16(Ah[ks][1], Bh, hh1, 0, 0, 0);
                hl1 = __builtin_amdgcn_mfma_f32_16x16x32_bf16(Ah[ks][1], Bl, hl1, 0, 0, 0);
                lh1 = __builtin_amdgcn_mfma_f32_16x16x32_bf16(Al[ks][1], Bh, lh1, 0, 0, 0);
            }
            f4 c0 = hh0 + hl0 + lh0;
            f4 c1 = hh1 + hl1 + lh1;
            *(f4*)&sPart[wid][0][p4][c][kg * 4] = c0;
            *(f4*)&sPart[wid][1][p4][c][kg * 4] = c1;
        }
        if (have) {
            stage_f4(sHi[cb ^ 1], sLo[cb ^ 1], tid, v0);
            stage_f4(sHi[cb ^ 1], sLo[cb ^ 1], tid + 320, v1);
            if (tid < 80) stage_f4(sHi[cb ^ 1], sLo[cb ^ 1], tid + 640, v2);
        }
        __syncthreads();
        for (int idx = tid; idx < 480; idx += 320) {
            int pix = idx / 30, oc = idx % 30;
            int m = oc >> 4, r = oc & 15;
            int py = pix >> 2, px = pix & 3;
            float vmax = -1e30f;
#pragma unroll
            for (int dy = 0; dy < 2; ++dy)
#pragma unroll
                for (int dx = 0; dx < 2; ++dx) {
                    int n = (2 * py + dy) * 8 + 2 * px + dx;
                    float s = 0.f;
#pragma unroll
                    for (int w = 0; w < 5; ++w)
                        s += sPart[w][m][n >> 4][n & 15][r];
                    vmax = fmaxf(vmax, s);
                }
            out[(b0 + img) * 480 + idx] = tanhf_fast(vmax + sB[oc]);
        }
        __syncthreads();
    }
}

// ---------- fused fc1(640->100)+tanh + fc2(100->10) + softmax ----------
__global__ __launch_bounds__(448) void fc_fused(
    const float* __restrict__ in, const short* __restrict__ wf1,
    const float* __restrict__ b1, const float* __restrict__ w2,
    const float* __restrict__ b2, float* __restrict__ out)
{
    constexpr int XS = 648;      // padded row stride (ushorts)
    __shared__ ushort_t sXh[16][XS];
    __shared__ ushort_t sXl[16][XS];
    __shared__ float    sG[16][116];
    __shared__ float    sF[16][101];
    __shared__ float    sW2[1000];
    __shared__ float    sB2[10];
    __shared__ float    sL[16][12];

    const int tid  = threadIdx.x;
    const int lane = tid & 63;
    const int wid  = tid >> 6;
    const int lr   = lane & 15;
    const int lg   = lane >> 4;
    const long b0  = (long)blockIdx.x * 16;

    for (int idx = tid; idx < 2560; idx += 448) {
        int flat = idx * 4;
        int row = flat / 640, col = flat % 640;
        float4 v = *(const float4*)(in + (b0 + row) * 640 + col);
        ushort_t h0 = bf16hi(v.x), h1 = bf16hi(v.y);
        ushort_t h2 = bf16hi(v.z), h3 = bf16hi(v.w);
        uint2 hp = { (uint_t)h0 | ((uint_t)h1 << 16), (uint_t)h2 | ((uint_t)h3 << 16) };
        ushort_t l0 = bf16hi(v.x - bf16tof(h0));
        ushort_t l1 = bf16hi(v.y - bf16tof(h1));
        ushort_t l2 = bf16hi(v.z - bf16tof(h2));
        ushort_t l3 = bf16hi(v.w - bf16tof(h3));
        uint2 lp = { (uint_t)l0 | ((uint_t)l1 << 16), (uint_t)l2 | ((uint_t)l3 << 16) };
        *(uint2*)&sXh[row][col] = hp;
        *(uint2*)&sXl[row][col] = lp;
    }
    for (int idx = tid; idx < 1000; idx += 448) sW2[idx] = w2[idx];
    if (tid < 10) sB2[tid] = b2[tid];

    f4 biasF;
#pragma unroll
    for (int q = 0; q < 4; ++q) {
        int rr = wid * 16 + lg * 4 + q;
        biasF[q] = (rr < 100) ? b1[rr] : 0.f;
    }
    __syncthreads();

    {
        const sh8* wfv = (const sh8*)wf1;
        f4 hh = biasF, hl = {0.f,0.f,0.f,0.f}, lh = {0.f,0.f,0.f,0.f};
#pragma unroll
        for (int ks = 0; ks < 20; ++ks) {
            int base = ((wid * 20 + ks) * 2) * 64 + lane;
            sh8 Ah = wfv[base];
            sh8 Al = wfv[base + 64];
            sh8 Bh = *(const sh8*)&sXh[lr][ks * 32 + lg * 8];
            sh8 Bl = *(const sh8*)&sXl[lr][ks * 32 + lg * 8];
            hh = __builtin_amdgcn_mfma_f32_16x16x32_bf16(Ah, Bh, hh, 0, 0, 0);
            hl = __builtin_amdgcn_mfma_f32_16x16x32_bf16(Ah, Bl, hl, 0, 0, 0);
            lh = __builtin_amdgcn_mfma_f32_16x16x32_bf16(Al, Bh, lh, 0, 0, 0);
        }
        f4 acc = hh + hl + lh;
        *(f4*)&sG[lr][wid * 16 + lg * 4] = acc;
    }
    __syncthreads();

    for (int idx = tid; idx < 1600; idx += 448) {
        int bb = idx / 100, o = idx % 100;
        sF[bb][o] = tanhf_fast(sG[bb][o]);
    }
    __syncthreads();

    if (tid < 160) {
        int o2 = tid >> 4, bb = tid & 15;
        const float* wr = &sW2[o2 * 100];
        float acc = sB2[o2];
        for (int k = 0; k < 100; ++k) acc += sF[bb][k] * wr[k];
        sL[bb][o2] = acc;
    }
    __syncthreads();

    if (tid < 16) {
        float lg10[10];
#pragma unroll
        for (int o = 0; o < 10; ++o) lg10[o] = sL[tid][o];
        float m = lg10[0];
#pragma unroll
        for (int o = 1; o < 10; ++o) m = fmaxf(m, lg10[o]);
        float s = 0.f;
#pragma unroll
        for (int o = 0; o < 10; ++o) { lg10[o] = __expf(lg10[o] - m); s += lg10[o]; }
        float inv = fast_rcp(s);
        float* ob = out + (b0 + tid) * 10;
#pragma unroll
        for (int o = 0; o < 10; ++o) ob[o] = lg10[o] * inv;
    }
}

extern "C" void kernel_launch(void* const* d_in, const int* in_sizes, int n_in,
                              void* d_out, int out_size, void* d_ws, size_t ws_size,
                              hipStream_t stream)
{
    const float* x    = (const float*)d_in[0];
    const float* c1w  = (const float*)d_in[1];
    const float* c1b  = (const float*)d_in[2];
    const float* m1Wx = (const float*)d_in[3];
    const float* m1Wl = (const float*)d_in[4];
    const float* m1Wu = (const float*)d_in[5];
    const float* m1b  = (const float*)d_in[6];
    const float* c2w  = (const float*)d_in[7];
    const float* c2b  = (const float*)d_in[8];
    const float* m2Wx = (const float*)d_in[9];
    const float* m2Wl = (const float*)d_in[10];
    const float* m2Wu = (const float*)d_in[11];
    const float* m2b  = (const float*)d_in[12];
    const float* f1w  = (const float*)d_in[13];
    const float* f1b  = (const float*)d_in[14];
    const float* f2w  = (const float*)d_in[15];
    const float* f2b  = (const float*)d_in[16];
    float* outp = (float*)d_out;

    char* ws = (char*)d_ws;
    float* a1 = (float*)ws;                 // [B,144,10] 23.6 MB
    float* h1 = (float*)(ws + 23592960);    // [B,144,20] 47.2 MB
    float* a2 = a1;                         // [B,16,30] 7.86 MB (reuse a1)
    short* wfrag  = (short*)(ws + 8388608); // 102 KB (dead-a1 region, > a2)
    short* wfrag1 = (short*)(ws + 9437184); // 286 KB (dead-a1 region)
    float* h2 = h1;                         // [B,16,40] reuse

    conv1_pool_tanh<<<2304, 256, 0, stream>>>(x, c1w, c1b, a1);
    // m1: H=12, HID=20, CIN=10, KV=64, NK=2, NWM=7, CSPL=2 -> 896 thr
    mdlstm_diag<12, 20, 10, 64, 2, 7, 2, 104><<<256, 896, 0, stream>>>(
        a1, m1Wx, m1Wl, m1Wu, m1b, h1);
    prep_conv2_frags<<<100, 256, 0, stream>>>(c2w, wfrag);    // a1 dead now
    prep_fc1_frags<<<560, 256, 0, stream>>>(f1w, wfrag1);
    conv2_mfma<<<256, 320, 0, stream>>>(h1, wfrag, c2b, a2);
    // m2: H=4, HID=40, CIN=30, KV=128, NK=4, NWM=13, CSPL=1 -> 832 thr
    mdlstm_diag<4, 40, 30, 128, 4, 13, 1, 212><<<256, 832, 0, stream>>>(
        a2, m2Wx, m2Wl, m2Wu, m2b, h2);
    fc_fused<<<256, 448, 0, stream>>>(h2, wfrag1, f1b, f2w, f2b, outp);
}